// Round 7
// baseline (185.077 us; speedup 1.0000x reference)
//
#include <hip/hip_runtime.h>
#include <hip/hip_bf16.h>

#define T_SEQ   2048
#define BATCH   2
#define DMODEL  1024
#define NHEADS  16
#define HDIM    64
#define WINDOW  128

typedef __attribute__((ext_vector_type(8))) short bf16x8;
typedef __attribute__((ext_vector_type(4))) float f32x4;

__device__ inline void unpack8(uint4 u, float* f) {
    unsigned int w[4] = {u.x, u.y, u.z, u.w};
#pragma unroll
    for (int i = 0; i < 4; i++) {
        f[2*i]   = __uint_as_float(w[i] << 16);
        f[2*i+1] = __uint_as_float(w[i] & 0xffff0000u);
    }
}

// async global->LDS 16B per lane; LDS dest is wave-uniform base + lane*16
__device__ inline void gld_lds16(const __hip_bfloat16* g, __hip_bfloat16* l) {
    __builtin_amdgcn_global_load_lds(
        (const __attribute__((address_space(1))) unsigned int*)g,
        (__attribute__((address_space(3))) unsigned int*)l, 16, 0, 0);
}

// fp32 -> bf16 bulk convert: y=0 -> x (4M), y=1..4 -> Wq/Wk/Wv/Wo (1M each)
__global__ __launch_bounds__(256) void cvt_kernel(
    const float* __restrict__ x,  const float* __restrict__ Wq,
    const float* __restrict__ Wk, const float* __restrict__ Wv,
    const float* __restrict__ Wo,
    __hip_bfloat16* __restrict__ xb, __hip_bfloat16* __restrict__ Wb)
{
    const int slot = blockIdx.y;
    const float* src;
    __hip_bfloat16* dst;
    int n;
    if (slot == 0) { src = x; dst = xb; n = 4 * 1024 * 1024; }
    else {
        src = (slot == 1) ? Wq : (slot == 2) ? Wk : (slot == 3) ? Wv : Wo;
        dst = Wb + (size_t)(slot - 1) * 1024 * 1024;
        n = 1024 * 1024;
    }
    int i = (blockIdx.x * 256 + threadIdx.x) * 8;
    if (i >= n) return;
    float4 a = *(const float4*)(src + i);
    float4 b = *(const float4*)(src + i + 4);
    __hip_bfloat16 pk[8] = {
        __float2bfloat16(a.x), __float2bfloat16(a.y),
        __float2bfloat16(a.z), __float2bfloat16(a.w),
        __float2bfloat16(b.x), __float2bfloat16(b.y),
        __float2bfloat16(b.z), __float2bfloat16(b.w)};
    *(uint4*)(dst + i) = *(uint4*)pk;
}

// QKV GEMM: C[M,128-col tile] = A[M,K] * W[N,K]^T, bf16, fp32 accum.
// 2 waves/block, block tile 128x128, wave tile 64x128 (acc[4][8]):
// LDS bytes per MAC halves vs 64x64 -> K-loop moves from LDS-read-bound
// (~1365 MAC/cyc/CU) to MFMA-pipe-bound (~1689). z<2 fuses per-head l2norm
// (head width 64 = ni groups 0-3 / 4-7 + shfl over col lanes).
__global__ __launch_bounds__(128) void gemm_qkv(
    const __hip_bfloat16* __restrict__ A,
    const __hip_bfloat16* __restrict__ W0,
    const __hip_bfloat16* __restrict__ W1,
    const __hip_bfloat16* __restrict__ W2,
    __hip_bfloat16* __restrict__ C0,
    __hip_bfloat16* __restrict__ C1,
    __hip_bfloat16* __restrict__ C2,
    int M, int N, int K)
{
    const int z = blockIdx.z;
    const __hip_bfloat16* W = (z == 0) ? W0 : (z == 1 ? W1 : W2);
    __hip_bfloat16* C = (z == 0) ? C0 : (z == 1 ? C1 : C2);

    const int n0 = blockIdx.x * 128;
    const int m0 = blockIdx.y * 128;

    __shared__ __hip_bfloat16 As[128 * 32];
    __shared__ __hip_bfloat16 Bs[128 * 32];

    const int t    = threadIdx.x;
    const int lane = t & 63;
    const int w    = t >> 6;          // wave 0..1

    // staging: wave w covers rows [w*64, w*64+64) of As and Bs (4 insts each)
    const int gc   = ((lane & 3) - (lane >> 3)) & 3;   // swizzled global chunk
    const int srow = w * 64 + (lane >> 2);
    const __hip_bfloat16* Ag = A + (size_t)(m0 + srow) * K + gc * 8;
    const __hip_bfloat16* Wg = W + (size_t)(n0 + srow) * K + gc * 8;
    const size_t row16 = (size_t)16 * K;
    __hip_bfloat16* AsD = &As[(w * 64) * 32];
    __hip_bfloat16* BsD = &Bs[(w * 64) * 32];

    const int wm   = w * 64;
    const int lrow = lane & 15;
    const int quad = lane >> 4;
    const int slot = ((quad + (lrow >> 1)) & 3) * 8;   // swizzled read slot

    f32x4 acc[4][8];
#pragma unroll
    for (int i = 0; i < 4; i++)
#pragma unroll
        for (int j = 0; j < 8; j++)
            acc[i][j] = (f32x4){0.f, 0.f, 0.f, 0.f};

    for (int k0 = 0; k0 < K; k0 += 32) {
#pragma unroll
        for (int i = 0; i < 4; i++) {
            gld_lds16(Ag + k0 + (size_t)i * row16, AsD + i * 16 * 32);
            gld_lds16(Wg + k0 + (size_t)i * row16, BsD + i * 16 * 32);
        }
        __syncthreads();

        bf16x8 af[4], bfv[8];
#pragma unroll
        for (int mi = 0; mi < 4; mi++)
            af[mi] = *(const bf16x8*)&As[(wm + mi * 16 + lrow) * 32 + slot];
#pragma unroll
        for (int ni = 0; ni < 8; ni++)
            bfv[ni] = *(const bf16x8*)&Bs[(ni * 16 + lrow) * 32 + slot];
#pragma unroll
        for (int mi = 0; mi < 4; mi++)
#pragma unroll
            for (int ni = 0; ni < 8; ni++)
                acc[mi][ni] = __builtin_amdgcn_mfma_f32_16x16x32_bf16(
                    af[mi], bfv[ni], acc[mi][ni], 0, 0, 0);
        __syncthreads();
    }

    // fused per-head l2norm for Q,K (z<2); heads = 64-col halves of the tile
    if (z != 2) {
#pragma unroll
        for (int mi = 0; mi < 4; mi++) {
#pragma unroll
            for (int rr = 0; rr < 4; rr++) {
#pragma unroll
                for (int hh = 0; hh < 2; hh++) {
                    float ss = 0.f;
#pragma unroll
                    for (int ni = 0; ni < 4; ni++) {
                        float v = acc[mi][hh * 4 + ni][rr];
                        ss += v * v;
                    }
                    ss += __shfl_xor(ss, 1);
                    ss += __shfl_xor(ss, 2);
                    ss += __shfl_xor(ss, 4);
                    ss += __shfl_xor(ss, 8);
                    float inv = 1.0f / fmaxf(sqrtf(ss), 1e-6f);
#pragma unroll
                    for (int ni = 0; ni < 4; ni++)
                        acc[mi][hh * 4 + ni][rr] *= inv;
                }
            }
        }
    }

    // epilogue: C/D layout col=lane&15, row=quad*4+reg  [verified m89/m91]
#pragma unroll
    for (int mi = 0; mi < 4; mi++) {
#pragma unroll
        for (int rr = 0; rr < 4; rr++) {
            int row = m0 + wm + mi * 16 + quad * 4 + rr;
            __hip_bfloat16* Crow = C + (size_t)row * N + n0 + lrow;
#pragma unroll
            for (int ni = 0; ni < 8; ni++)
                Crow[ni * 16] = __float2bfloat16(acc[mi][ni][rr]);
        }
    }
}

// O-projection GEMM: 64x128 tile, 4 waves (2x2 of 32x64... actually MI=2),
// fp32 C output. Same staging/swizzle invariants as gemm_qkv.
__global__ __launch_bounds__(256) void gemm_o(
    const __hip_bfloat16* __restrict__ A,
    const __hip_bfloat16* __restrict__ W,
    float* __restrict__ C,
    int M, int N, int K)
{
    const int n0 = blockIdx.x * 128;
    const int m0 = blockIdx.y * 64;

    __shared__ __hip_bfloat16 As[64 * 32];
    __shared__ __hip_bfloat16 Bs[128 * 32];

    const int t    = threadIdx.x;
    const int lane = t & 63;
    const int wv   = t >> 6;

    const int gc    = ((lane & 3) - (lane >> 3)) & 3;
    const int srowA = wv * 16 + (lane >> 2);
    const int srowB = wv * 32 + (lane >> 2);
    const __hip_bfloat16* Ag = A + (size_t)(m0 + srowA) * K + gc * 8;
    const __hip_bfloat16* Wg = W + (size_t)(n0 + srowB) * K + gc * 8;
    const size_t row16 = (size_t)16 * K;
    __hip_bfloat16* AsD0 = &As[(wv * 16) * 32];
    __hip_bfloat16* BsD0 = &Bs[(wv * 32) * 32];
    __hip_bfloat16* BsD1 = &Bs[(wv * 32 + 16) * 32];

    const int wm   = (wv >> 1) * 32;
    const int wn   = (wv & 1) * 64;
    const int lrow = lane & 15;
    const int quad = lane >> 4;
    const int slot = ((quad + (lrow >> 1)) & 3) * 8;

    f32x4 acc[2][4];
#pragma unroll
    for (int i = 0; i < 2; i++)
#pragma unroll
        for (int j = 0; j < 4; j++)
            acc[i][j] = (f32x4){0.f, 0.f, 0.f, 0.f};

    for (int k0 = 0; k0 < K; k0 += 32) {
        gld_lds16(Ag + k0, AsD0);
        gld_lds16(Wg + k0,         BsD0);
        gld_lds16(Wg + k0 + row16, BsD1);
        __syncthreads();

        bf16x8 af[2], bfv[4];
#pragma unroll
        for (int mi = 0; mi < 2; mi++)
            af[mi] = *(const bf16x8*)&As[(wm + mi * 16 + lrow) * 32 + slot];
#pragma unroll
        for (int ni = 0; ni < 4; ni++)
            bfv[ni] = *(const bf16x8*)&Bs[(wn + ni * 16 + lrow) * 32 + slot];
#pragma unroll
        for (int mi = 0; mi < 2; mi++)
#pragma unroll
            for (int ni = 0; ni < 4; ni++)
                acc[mi][ni] = __builtin_amdgcn_mfma_f32_16x16x32_bf16(
                    af[mi], bfv[ni], acc[mi][ni], 0, 0, 0);
        __syncthreads();
    }

#pragma unroll
    for (int mi = 0; mi < 2; mi++) {
#pragma unroll
        for (int rr = 0; rr < 4; rr++) {
            int row = m0 + wm + mi * 16 + quad * 4 + rr;
            float* Crow = C + (size_t)row * N + n0 + wn + lrow;
#pragma unroll
            for (int ni = 0; ni < 4; ni++)
                Crow[ni * 16] = acc[mi][ni][rr];
        }
    }
}

// MFMA sliding-window attention. Block = 256 thr = one (b,h) x 64-query tile.
// LDS = 52 KB exactly -> 3 blocks/CU.
__global__ __launch_bounds__(256) void attn_kernel(
    const __hip_bfloat16* __restrict__ Q,
    const __hip_bfloat16* __restrict__ K,
    const __hip_bfloat16* __restrict__ V,
    __hip_bfloat16* __restrict__ O)
{
    const int i0 = blockIdx.x * 64;
    const int h  = blockIdx.y;
    const int b  = blockIdx.z;

    __shared__ __hip_bfloat16 Ks[192 * 72];   // keys band; P overlay later
    __shared__ __hip_bfloat16 Vt[64 * 200];   // V^T, swizzled key blocks

    const size_t base = ((size_t)b * T_SEQ) * DMODEL + h * HDIM;
    const int t = threadIdx.x;

    // K staging: b128 rows, stride 72 (2-way free)
    for (int task = t; task < 192 * 8; task += 256) {
        int row = task >> 3;
        int c   = task & 7;
        int j   = min(i0 + row, T_SEQ - 1);
        *(uint4*)&Ks[row * 72 + c * 8] = *(const uint4*)(K + base + (size_t)j * DMODEL + c * 8);
    }
    // V staging: 8x8 register transpose, swizzled b128 writes
    for (int task = t; task < 192; task += 256) {
        int c  = task & 7;            // dim chunk
        int r0 = (task >> 3) * 8;     // key block start
        int b0 = task >> 3;           // key block index (0..23)
        unsigned short m[8][8];
#pragma unroll
        for (int i = 0; i < 8; i++) {
            int j = min(i0 + r0 + i, T_SEQ - 1);
            uint4 u = *(const uint4*)(V + base + (size_t)j * DMODEL + c * 8);
            unsigned short tmp[8];
            *(uint4*)tmp = u;
#pragma unroll
            for (int e = 0; e < 8; e++) m[e][i] = tmp[e];
        }
#pragma unroll
        for (int e = 0; e < 8; e++) {
            int d  = c * 8 + e;
            int sg = (b0 & ~7) | ((b0 + (d >> 3)) & 7);
            *(uint4*)&Vt[d * 200 + sg * 8] = *(uint4*)m[e];
        }
    }
    // zero slot 24 (tail keys; P is zero there but data must be finite)
    for (int task = t; task < 64; task += 256) {
        uint4 zz = {0, 0, 0, 0};
        *(uint4*)&Vt[task * 200 + 192] = zz;
    }
    __syncthreads();

    const int lane = t & 63;
    const int w    = t >> 6;
    const int col  = lane & 15;
    const int quad = lane >> 4;
    const float slope = exp2f(-8.0f * (float)h / 15.0f);

    const __hip_bfloat16* qp = Q + base + (size_t)(i0 + w * 16 + col) * DMODEL + quad * 8;
    bf16x8 qf0 = *(const bf16x8*)(qp);
    bf16x8 qf1 = *(const bf16x8*)(qp + 32);

    f32x4 sc[9];
#pragma unroll
    for (int kt = 0; kt < 9; kt++) {
        sc[kt] = (f32x4){0.f, 0.f, 0.f, 0.f};
        const __hip_bfloat16* kr = &Ks[(w * 16 + kt * 16 + col) * 72 + quad * 8];
        bf16x8 kb0 = *(const bf16x8*)(kr);
        bf16x8 kb1 = *(const bf16x8*)(kr + 32);
        sc[kt] = __builtin_amdgcn_mfma_f32_16x16x32_bf16(qf0, kb0, sc[kt], 0, 0, 0);
        sc[kt] = __builtin_amdgcn_mfma_f32_16x16x32_bf16(qf1, kb1, sc[kt], 0, 0, 0);
    }

    float mx[4] = {-3e38f, -3e38f, -3e38f, -3e38f};
#pragma unroll
    for (int kt = 0; kt < 9; kt++) {
#pragma unroll
        for (int r = 0; r < 4; r++) {
            int ql  = quad * 4 + r;
            int rel = kt * 16 + col - ql;
            int ka  = i0 + w * 16 + kt * 16 + col;
            bool valid = (rel >= 0) && (rel < WINDOW) && (ka < T_SEQ);
            float v = valid ? (sc[kt][r] - (float)rel * slope) : -1e30f;
            sc[kt][r] = v;
            mx[r] = fmaxf(mx[r], v);
        }
    }
#pragma unroll
    for (int r = 0; r < 4; r++) {
        mx[r] = fmaxf(mx[r], __shfl_xor(mx[r], 1));
        mx[r] = fmaxf(mx[r], __shfl_xor(mx[r], 2));
        mx[r] = fmaxf(mx[r], __shfl_xor(mx[r], 4));
        mx[r] = fmaxf(mx[r], __shfl_xor(mx[r], 8));
    }
    float sm[4] = {0.f, 0.f, 0.f, 0.f};
#pragma unroll
    for (int kt = 0; kt < 9; kt++) {
#pragma unroll
        for (int r = 0; r < 4; r++) {
            float e = __expf(sc[kt][r] - mx[r]);
            sc[kt][r] = e;
            sm[r] += e;
        }
    }
#pragma unroll
    for (int r = 0; r < 4; r++) {
        sm[r] += __shfl_xor(sm[r], 1);
        sm[r] += __shfl_xor(sm[r], 2);
        sm[r] += __shfl_xor(sm[r], 4);
        sm[r] += __shfl_xor(sm[r], 8);
        sm[r] = 1.0f / sm[r];
    }

    // all Ks reads done -> overlay P (per-wave region, stride 168)
    __syncthreads();
    __hip_bfloat16* Ps = Ks + w * (16 * 168);
#pragma unroll
    for (int kt = 0; kt < 9; kt++)
#pragma unroll
        for (int r = 0; r < 4; r++)
            Ps[(quad * 4 + r) * 168 + kt * 16 + col] = __float2bfloat16(sc[kt][r] * sm[r]);
#pragma unroll
    for (int i = 0; i < 4; i++)
        Ps[(lane & 15) * 168 + 144 + quad * 4 + i] = __float2bfloat16(0.f);
    __syncthreads();

    // PV: A = P[q][key], B = Vt[dim][key] (swizzled slots)
    f32x4 o[4];
#pragma unroll
    for (int nd = 0; nd < 4; nd++) o[nd] = (f32x4){0.f, 0.f, 0.f, 0.f};
#pragma unroll
    for (int kc = 0; kc < 5; kc++) {
        bf16x8 pf = *(const bf16x8*)&Ps[col * 168 + kc * 32 + quad * 8];
        int bblk = w * 2 + kc * 4 + quad;
#pragma unroll
        for (int nd = 0; nd < 4; nd++) {
            int d  = nd * 16 + col;
            int sg = (bblk < 24) ? ((bblk & ~7) | ((bblk + (d >> 3)) & 7)) : 24;
            bf16x8 vf = *(const bf16x8*)&Vt[d * 200 + sg * 8];
            o[nd] = __builtin_amdgcn_mfma_f32_16x16x32_bf16(pf, vf, o[nd], 0, 0, 0);
        }
    }

#pragma unroll
    for (int r = 0; r < 4; r++) {
        __hip_bfloat16* op = O + base + (size_t)(i0 + w * 16 + quad * 4 + r) * DMODEL + col;
#pragma unroll
        for (int nd = 0; nd < 4; nd++)
            op[nd * 16] = __float2bfloat16(o[nd][r]);
    }
}

extern "C" void kernel_launch(void* const* d_in, const int* in_sizes, int n_in,
                              void* d_out, int out_size, void* d_ws, size_t ws_size,
                              hipStream_t stream)
{
    const float* x  = (const float*)d_in[0];
    const float* Wq = (const float*)d_in[1];
    const float* Wk = (const float*)d_in[2];
    const float* Wv = (const float*)d_in[3];
    const float* Wo = (const float*)d_in[4];
    float* out = (float*)d_out;

    const size_t MT = (size_t)BATCH * T_SEQ;          // 4096 rows
    __hip_bfloat16* Qw = (__hip_bfloat16*)d_ws;       // 8 MB each (bf16)
    __hip_bfloat16* Kw = Qw + MT * DMODEL;
    __hip_bfloat16* Vw = Kw + MT * DMODEL;
    __hip_bfloat16* XA = Vw + MT * DMODEL;            // xb (pre-attn) / AO (post-attn)
    __hip_bfloat16* Wb = XA + MT * DMODEL;            // 4 x 1M bf16 weights

    cvt_kernel<<<dim3(2048, 5), 256, 0, stream>>>(x, Wq, Wk, Wv, Wo, XA, Wb);

    dim3 g1(DMODEL / 128, MT / 128, 3);
    gemm_qkv<<<g1, 128, 0, stream>>>(
        XA, Wb, Wb + 1024 * 1024, Wb + 2 * 1024 * 1024,
        Qw, Kw, Vw, (int)MT, DMODEL, DMODEL);

    dim3 g2(T_SEQ / 64, NHEADS, BATCH);
    attn_kernel<<<g2, 256, 0, stream>>>(Qw, Kw, Vw, XA);

    dim3 g3(DMODEL / 128, MT / 64, 1);
    gemm_o<<<g3, 256, 0, stream>>>(
        XA, Wb + 3 * 1024 * 1024, out, (int)MT, DMODEL, DMODEL);
}

// Round 8
// 155.750 us; speedup vs baseline: 1.1883x; 1.1883x over previous
//
#include <hip/hip_runtime.h>
#include <hip/hip_bf16.h>

#define T_SEQ   2048
#define BATCH   2
#define DMODEL  1024
#define NHEADS  16
#define HDIM    64
#define WINDOW  128

typedef __attribute__((ext_vector_type(8))) short bf16x8;
typedef __attribute__((ext_vector_type(4))) float f32x4;

__device__ inline void unpack8(uint4 u, float* f) {
    unsigned int w[4] = {u.x, u.y, u.z, u.w};
#pragma unroll
    for (int i = 0; i < 4; i++) {
        f[2*i]   = __uint_as_float(w[i] << 16);
        f[2*i+1] = __uint_as_float(w[i] & 0xffff0000u);
    }
}

// async global->LDS 16B per lane; LDS dest is wave-uniform base + lane*16
__device__ inline void gld_lds16(const __hip_bfloat16* g, __hip_bfloat16* l) {
    __builtin_amdgcn_global_load_lds(
        (const __attribute__((address_space(1))) unsigned int*)g,
        (__attribute__((address_space(3))) unsigned int*)l, 16, 0, 0);
}

// fp32 -> bf16 bulk convert: y=0 -> x (4M), y=1..4 -> Wq/Wk/Wv/Wo (1M each)
__global__ __launch_bounds__(256) void cvt_kernel(
    const float* __restrict__ x,  const float* __restrict__ Wq,
    const float* __restrict__ Wk, const float* __restrict__ Wv,
    const float* __restrict__ Wo,
    __hip_bfloat16* __restrict__ xb, __hip_bfloat16* __restrict__ Wb)
{
    const int slot = blockIdx.y;
    const float* src;
    __hip_bfloat16* dst;
    int n;
    if (slot == 0) { src = x; dst = xb; n = 4 * 1024 * 1024; }
    else {
        src = (slot == 1) ? Wq : (slot == 2) ? Wk : (slot == 3) ? Wv : Wo;
        dst = Wb + (size_t)(slot - 1) * 1024 * 1024;
        n = 1024 * 1024;
    }
    int i = (blockIdx.x * 256 + threadIdx.x) * 8;
    if (i >= n) return;
    float4 a = *(const float4*)(src + i);
    float4 b = *(const float4*)(src + i + 4);
    __hip_bfloat16 pk[8] = {
        __float2bfloat16(a.x), __float2bfloat16(a.y),
        __float2bfloat16(a.z), __float2bfloat16(a.w),
        __float2bfloat16(b.x), __float2bfloat16(b.y),
        __float2bfloat16(b.z), __float2bfloat16(b.w)};
    *(uint4*)(dst + i) = *(uint4*)pk;
}

// QKV GEMM: C = A[M,K] * W[N,K]^T, bf16, fp32 accum. z selects (W,C) pair.
// PROVEN SHAPE (R5): 256 thr = 4 waves (2x2 of 64x64), 128x128 tile, BK=32,
// unpadded LDS + global_load_lds dwordx4, chunk swizzle for 2-way LDS reads.
// NOTE: 2-wave/64x128 variant regressed 3x (R7: occupancy 9%, MfmaUtil 10%)
// — 4 waves/block x ~3 blocks/CU of barrier overlap is what sustains ~870 TF.
// z<2 fuses per-head l2norm (head width 64 = wave n-extent, 4 shfl_xor).
__global__ __launch_bounds__(256) void gemm_qkv(
    const __hip_bfloat16* __restrict__ A,
    const __hip_bfloat16* __restrict__ W0,
    const __hip_bfloat16* __restrict__ W1,
    const __hip_bfloat16* __restrict__ W2,
    __hip_bfloat16* __restrict__ C0,
    __hip_bfloat16* __restrict__ C1,
    __hip_bfloat16* __restrict__ C2,
    int M, int N, int K)
{
    const int z = blockIdx.z;
    const __hip_bfloat16* W = (z == 0) ? W0 : (z == 1 ? W1 : W2);
    __hip_bfloat16* C = (z == 0) ? C0 : (z == 1 ? C1 : C2);

    const int n0 = blockIdx.x * 128;
    const int m0 = blockIdx.y * 128;

    __shared__ __hip_bfloat16 As[128 * 32];
    __shared__ __hip_bfloat16 Bs[128 * 32];

    const int t    = threadIdx.x;
    const int lane = t & 63;
    const int wv   = t >> 6;

    // staging: wave wv covers rows [wv*32, wv*32+32), 2 insts of 16 rows each
    const int gc   = ((lane & 3) - (lane >> 3)) & 3;   // swizzled global chunk
    const int srow = wv * 32 + (lane >> 2);
    const __hip_bfloat16* Ag = A + (size_t)(m0 + srow) * K + gc * 8;
    const __hip_bfloat16* Wg = W + (size_t)(n0 + srow) * K + gc * 8;
    const size_t row16 = (size_t)16 * K;
    __hip_bfloat16* AsD0 = &As[(wv * 32) * 32];
    __hip_bfloat16* AsD1 = &As[(wv * 32 + 16) * 32];
    __hip_bfloat16* BsD0 = &Bs[(wv * 32) * 32];
    __hip_bfloat16* BsD1 = &Bs[(wv * 32 + 16) * 32];

    const int wm   = (wv >> 1) * 64;
    const int wn   = (wv & 1) * 64;
    const int lrow = lane & 15;
    const int quad = lane >> 4;
    const int slot = ((quad + (lrow >> 1)) & 3) * 8;   // swizzled read slot

    f32x4 acc[4][4];
#pragma unroll
    for (int i = 0; i < 4; i++)
#pragma unroll
        for (int j = 0; j < 4; j++)
            acc[i][j] = (f32x4){0.f, 0.f, 0.f, 0.f};

    for (int k0 = 0; k0 < K; k0 += 32) {
        gld_lds16(Ag + k0,         AsD0);
        gld_lds16(Ag + k0 + row16, AsD1);
        gld_lds16(Wg + k0,         BsD0);
        gld_lds16(Wg + k0 + row16, BsD1);
        __syncthreads();

        bf16x8 af[4], bfv[4];
#pragma unroll
        for (int mi = 0; mi < 4; mi++)
            af[mi] = *(const bf16x8*)&As[(wm + mi * 16 + lrow) * 32 + slot];
#pragma unroll
        for (int ni = 0; ni < 4; ni++)
            bfv[ni] = *(const bf16x8*)&Bs[(wn + ni * 16 + lrow) * 32 + slot];
#pragma unroll
        for (int mi = 0; mi < 4; mi++)
#pragma unroll
            for (int ni = 0; ni < 4; ni++)
                acc[mi][ni] = __builtin_amdgcn_mfma_f32_16x16x32_bf16(
                    af[mi], bfv[ni], acc[mi][ni], 0, 0, 0);
        __syncthreads();
    }

    // fused per-head l2norm for Q,K (z<2): head = the wave's 64-col extent
    if (z != 2) {
#pragma unroll
        for (int mi = 0; mi < 4; mi++) {
#pragma unroll
            for (int rr = 0; rr < 4; rr++) {
                float ss = 0.f;
#pragma unroll
                for (int ni = 0; ni < 4; ni++)
                    ss += acc[mi][ni][rr] * acc[mi][ni][rr];
                ss += __shfl_xor(ss, 1);
                ss += __shfl_xor(ss, 2);
                ss += __shfl_xor(ss, 4);
                ss += __shfl_xor(ss, 8);
                float inv = 1.0f / fmaxf(sqrtf(ss), 1e-6f);
#pragma unroll
                for (int ni = 0; ni < 4; ni++)
                    acc[mi][ni][rr] *= inv;
            }
        }
    }

    // epilogue: C/D layout col=lane&15, row=quad*4+reg  [verified m89/m91]
#pragma unroll
    for (int mi = 0; mi < 4; mi++) {
#pragma unroll
        for (int rr = 0; rr < 4; rr++) {
            int row = m0 + wm + mi * 16 + quad * 4 + rr;
            __hip_bfloat16* Crow = C + (size_t)row * N + n0 + wn + lrow;
#pragma unroll
            for (int ni = 0; ni < 4; ni++)
                Crow[ni * 16] = __float2bfloat16(acc[mi][ni][rr]);
        }
    }
}

// O-projection GEMM: 64x128 tile, 4 waves (2x2 of 32x64), fp32 C output.
// 512 blocks -> 2 blocks/CU resident (vs 1 at 128-row tiles).
__global__ __launch_bounds__(256) void gemm_o(
    const __hip_bfloat16* __restrict__ A,
    const __hip_bfloat16* __restrict__ W,
    float* __restrict__ C,
    int M, int N, int K)
{
    const int n0 = blockIdx.x * 128;
    const int m0 = blockIdx.y * 64;

    __shared__ __hip_bfloat16 As[64 * 32];
    __shared__ __hip_bfloat16 Bs[128 * 32];

    const int t    = threadIdx.x;
    const int lane = t & 63;
    const int wv   = t >> 6;

    const int gc    = ((lane & 3) - (lane >> 3)) & 3;
    const int srowA = wv * 16 + (lane >> 2);
    const int srowB = wv * 32 + (lane >> 2);
    const __hip_bfloat16* Ag = A + (size_t)(m0 + srowA) * K + gc * 8;
    const __hip_bfloat16* Wg = W + (size_t)(n0 + srowB) * K + gc * 8;
    const size_t row16 = (size_t)16 * K;
    __hip_bfloat16* AsD0 = &As[(wv * 16) * 32];
    __hip_bfloat16* BsD0 = &Bs[(wv * 32) * 32];
    __hip_bfloat16* BsD1 = &Bs[(wv * 32 + 16) * 32];

    const int wm   = (wv >> 1) * 32;
    const int wn   = (wv & 1) * 64;
    const int lrow = lane & 15;
    const int quad = lane >> 4;
    const int slot = ((quad + (lrow >> 1)) & 3) * 8;

    f32x4 acc[2][4];
#pragma unroll
    for (int i = 0; i < 2; i++)
#pragma unroll
        for (int j = 0; j < 4; j++)
            acc[i][j] = (f32x4){0.f, 0.f, 0.f, 0.f};

    for (int k0 = 0; k0 < K; k0 += 32) {
        gld_lds16(Ag + k0, AsD0);
        gld_lds16(Wg + k0,         BsD0);
        gld_lds16(Wg + k0 + row16, BsD1);
        __syncthreads();

        bf16x8 af[2], bfv[4];
#pragma unroll
        for (int mi = 0; mi < 2; mi++)
            af[mi] = *(const bf16x8*)&As[(wm + mi * 16 + lrow) * 32 + slot];
#pragma unroll
        for (int ni = 0; ni < 4; ni++)
            bfv[ni] = *(const bf16x8*)&Bs[(wn + ni * 16 + lrow) * 32 + slot];
#pragma unroll
        for (int mi = 0; mi < 2; mi++)
#pragma unroll
            for (int ni = 0; ni < 4; ni++)
                acc[mi][ni] = __builtin_amdgcn_mfma_f32_16x16x32_bf16(
                    af[mi], bfv[ni], acc[mi][ni], 0, 0, 0);
        __syncthreads();
    }

#pragma unroll
    for (int mi = 0; mi < 2; mi++) {
#pragma unroll
        for (int rr = 0; rr < 4; rr++) {
            int row = m0 + wm + mi * 16 + quad * 4 + rr;
            float* Crow = C + (size_t)row * N + n0 + wn + lrow;
#pragma unroll
            for (int ni = 0; ni < 4; ni++)
                Crow[ni * 16] = acc[mi][ni][rr];
        }
    }
}

// MFMA sliding-window attention. Block = 256 thr = one (b,h) x 64-query tile.
// LDS = 52 KB exactly -> 3 blocks/CU.
__global__ __launch_bounds__(256) void attn_kernel(
    const __hip_bfloat16* __restrict__ Q,
    const __hip_bfloat16* __restrict__ K,
    const __hip_bfloat16* __restrict__ V,
    __hip_bfloat16* __restrict__ O)
{
    const int i0 = blockIdx.x * 64;
    const int h  = blockIdx.y;
    const int b  = blockIdx.z;

    __shared__ __hip_bfloat16 Ks[192 * 72];   // keys band; P overlay later
    __shared__ __hip_bfloat16 Vt[64 * 200];   // V^T, swizzled key blocks

    const size_t base = ((size_t)b * T_SEQ) * DMODEL + h * HDIM;
    const int t = threadIdx.x;

    // K staging: b128 rows, stride 72 (2-way free)
    for (int task = t; task < 192 * 8; task += 256) {
        int row = task >> 3;
        int c   = task & 7;
        int j   = min(i0 + row, T_SEQ - 1);
        *(uint4*)&Ks[row * 72 + c * 8] = *(const uint4*)(K + base + (size_t)j * DMODEL + c * 8);
    }
    // V staging: 8x8 register transpose, swizzled b128 writes
    for (int task = t; task < 192; task += 256) {
        int c  = task & 7;            // dim chunk
        int r0 = (task >> 3) * 8;     // key block start
        int b0 = task >> 3;           // key block index (0..23)
        unsigned short m[8][8];
#pragma unroll
        for (int i = 0; i < 8; i++) {
            int j = min(i0 + r0 + i, T_SEQ - 1);
            uint4 u = *(const uint4*)(V + base + (size_t)j * DMODEL + c * 8);
            unsigned short tmp[8];
            *(uint4*)tmp = u;
#pragma unroll
            for (int e = 0; e < 8; e++) m[e][i] = tmp[e];
        }
#pragma unroll
        for (int e = 0; e < 8; e++) {
            int d  = c * 8 + e;
            int sg = (b0 & ~7) | ((b0 + (d >> 3)) & 7);
            *(uint4*)&Vt[d * 200 + sg * 8] = *(uint4*)m[e];
        }
    }
    // zero slot 24 (tail keys; P is zero there but data must be finite)
    for (int task = t; task < 64; task += 256) {
        uint4 zz = {0, 0, 0, 0};
        *(uint4*)&Vt[task * 200 + 192] = zz;
    }
    __syncthreads();

    const int lane = t & 63;
    const int w    = t >> 6;
    const int col  = lane & 15;
    const int quad = lane >> 4;
    const float slope = exp2f(-8.0f * (float)h / 15.0f);

    const __hip_bfloat16* qp = Q + base + (size_t)(i0 + w * 16 + col) * DMODEL + quad * 8;
    bf16x8 qf0 = *(const bf16x8*)(qp);
    bf16x8 qf1 = *(const bf16x8*)(qp + 32);

    f32x4 sc[9];
#pragma unroll
    for (int kt = 0; kt < 9; kt++) {
        sc[kt] = (f32x4){0.f, 0.f, 0.f, 0.f};
        const __hip_bfloat16* kr = &Ks[(w * 16 + kt * 16 + col) * 72 + quad * 8];
        bf16x8 kb0 = *(const bf16x8*)(kr);
        bf16x8 kb1 = *(const bf16x8*)(kr + 32);
        sc[kt] = __builtin_amdgcn_mfma_f32_16x16x32_bf16(qf0, kb0, sc[kt], 0, 0, 0);
        sc[kt] = __builtin_amdgcn_mfma_f32_16x16x32_bf16(qf1, kb1, sc[kt], 0, 0, 0);
    }

    float mx[4] = {-3e38f, -3e38f, -3e38f, -3e38f};
#pragma unroll
    for (int kt = 0; kt < 9; kt++) {
#pragma unroll
        for (int r = 0; r < 4; r++) {
            int ql  = quad * 4 + r;
            int rel = kt * 16 + col - ql;
            int ka  = i0 + w * 16 + kt * 16 + col;
            bool valid = (rel >= 0) && (rel < WINDOW) && (ka < T_SEQ);
            float v = valid ? (sc[kt][r] - (float)rel * slope) : -1e30f;
            sc[kt][r] = v;
            mx[r] = fmaxf(mx[r], v);
        }
    }
#pragma unroll
    for (int r = 0; r < 4; r++) {
        mx[r] = fmaxf(mx[r], __shfl_xor(mx[r], 1));
        mx[r] = fmaxf(mx[r], __shfl_xor(mx[r], 2));
        mx[r] = fmaxf(mx[r], __shfl_xor(mx[r], 4));
        mx[r] = fmaxf(mx[r], __shfl_xor(mx[r], 8));
    }
    float sm[4] = {0.f, 0.f, 0.f, 0.f};
#pragma unroll
    for (int kt = 0; kt < 9; kt++) {
#pragma unroll
        for (int r = 0; r < 4; r++) {
            float e = __expf(sc[kt][r] - mx[r]);
            sc[kt][r] = e;
            sm[r] += e;
        }
    }
#pragma unroll
    for (int r = 0; r < 4; r++) {
        sm[r] += __shfl_xor(sm[r], 1);
        sm[r] += __shfl_xor(sm[r], 2);
        sm[r] += __shfl_xor(sm[r], 4);
        sm[r] += __shfl_xor(sm[r], 8);
        sm[r] = 1.0f / sm[r];
    }

    // all Ks reads done -> overlay P (per-wave region, stride 168)
    __syncthreads();
    __hip_bfloat16* Ps = Ks + w * (16 * 168);
#pragma unroll
    for (int kt = 0; kt < 9; kt++)
#pragma unroll
        for (int r = 0; r < 4; r++)
            Ps[(quad * 4 + r) * 168 + kt * 16 + col] = __float2bfloat16(sc[kt][r] * sm[r]);
#pragma unroll
    for (int i = 0; i < 4; i++)
        Ps[(lane & 15) * 168 + 144 + quad * 4 + i] = __float2bfloat16(0.f);
    __syncthreads();

    // PV: A = P[q][key], B = Vt[dim][key] (swizzled slots)
    f32x4 o[4];
#pragma unroll
    for (int nd = 0; nd < 4; nd++) o[nd] = (f32x4){0.f, 0.f, 0.f, 0.f};
#pragma unroll
    for (int kc = 0; kc < 5; kc++) {
        bf16x8 pf = *(const bf16x8*)&Ps[col * 168 + kc * 32 + quad * 8];
        int bblk = w * 2 + kc * 4 + quad;
#pragma unroll
        for (int nd = 0; nd < 4; nd++) {
            int d  = nd * 16 + col;
            int sg = (bblk < 24) ? ((bblk & ~7) | ((bblk + (d >> 3)) & 7)) : 24;
            bf16x8 vf = *(const bf16x8*)&Vt[d * 200 + sg * 8];
            o[nd] = __builtin_amdgcn_mfma_f32_16x16x32_bf16(pf, vf, o[nd], 0, 0, 0);
        }
    }

#pragma unroll
    for (int r = 0; r < 4; r++) {
        __hip_bfloat16* op = O + base + (size_t)(i0 + w * 16 + quad * 4 + r) * DMODEL + col;
#pragma unroll
        for (int nd = 0; nd < 4; nd++)
            op[nd * 16] = __float2bfloat16(o[nd][r]);
    }
}

extern "C" void kernel_launch(void* const* d_in, const int* in_sizes, int n_in,
                              void* d_out, int out_size, void* d_ws, size_t ws_size,
                              hipStream_t stream)
{
    const float* x  = (const float*)d_in[0];
    const float* Wq = (const float*)d_in[1];
    const float* Wk = (const float*)d_in[2];
    const float* Wv = (const float*)d_in[3];
    const float* Wo = (const float*)d_in[4];
    float* out = (float*)d_out;

    const size_t MT = (size_t)BATCH * T_SEQ;          // 4096 rows
    __hip_bfloat16* Qw = (__hip_bfloat16*)d_ws;       // 8 MB each (bf16)
    __hip_bfloat16* Kw = Qw + MT * DMODEL;
    __hip_bfloat16* Vw = Kw + MT * DMODEL;
    __hip_bfloat16* XA = Vw + MT * DMODEL;            // xb (pre-attn) / AO (post-attn)
    __hip_bfloat16* Wb = XA + MT * DMODEL;            // 4 x 1M bf16 weights

    cvt_kernel<<<dim3(2048, 5), 256, 0, stream>>>(x, Wq, Wk, Wv, Wo, XA, Wb);

    dim3 g1(DMODEL / 128, MT / 128, 3);
    gemm_qkv<<<g1, 256, 0, stream>>>(
        XA, Wb, Wb + 1024 * 1024, Wb + 2 * 1024 * 1024,
        Qw, Kw, Vw, (int)MT, DMODEL, DMODEL);

    dim3 g2(T_SEQ / 64, NHEADS, BATCH);
    attn_kernel<<<g2, 256, 0, stream>>>(Qw, Kw, Vw, XA);

    dim3 g3(DMODEL / 128, MT / 64, 1);
    gemm_o<<<g3, 256, 0, stream>>>(
        XA, Wb + 3 * 1024 * 1024, out, (int)MT, DMODEL, DMODEL);
}

// Round 9
// 153.780 us; speedup vs baseline: 1.2035x; 1.0128x over previous
//
#include <hip/hip_runtime.h>
#include <hip/hip_bf16.h>

#define T_SEQ   2048
#define BATCH   2
#define DMODEL  1024
#define NHEADS  16
#define HDIM    64
#define WINDOW  128

typedef __attribute__((ext_vector_type(8))) short bf16x8;
typedef __attribute__((ext_vector_type(4))) float f32x4;

__device__ inline void unpack8(uint4 u, float* f) {
    unsigned int w[4] = {u.x, u.y, u.z, u.w};
#pragma unroll
    for (int i = 0; i < 4; i++) {
        f[2*i]   = __uint_as_float(w[i] << 16);
        f[2*i+1] = __uint_as_float(w[i] & 0xffff0000u);
    }
}

// async global->LDS 16B per lane; LDS dest = wave-uniform base + lane*16
__device__ inline void gld_lds16(const __hip_bfloat16* g, __hip_bfloat16* l) {
    __builtin_amdgcn_global_load_lds(
        (const __attribute__((address_space(1))) unsigned int*)g,
        (__attribute__((address_space(3))) unsigned int*)l, 16, 0, 0);
}

// fp32 -> bf16 bulk convert: y=0 -> x (4M), y=1..4 -> Wq/Wk/Wv/Wo (1M each)
__global__ __launch_bounds__(256) void cvt_kernel(
    const float* __restrict__ x,  const float* __restrict__ Wq,
    const float* __restrict__ Wk, const float* __restrict__ Wv,
    const float* __restrict__ Wo,
    __hip_bfloat16* __restrict__ xb, __hip_bfloat16* __restrict__ Wb)
{
    const int slot = blockIdx.y;
    const float* src;
    __hip_bfloat16* dst;
    int n;
    if (slot == 0) { src = x; dst = xb; n = 4 * 1024 * 1024; }
    else {
        src = (slot == 1) ? Wq : (slot == 2) ? Wk : (slot == 3) ? Wv : Wo;
        dst = Wb + (size_t)(slot - 1) * 1024 * 1024;
        n = 1024 * 1024;
    }
    int i = (blockIdx.x * 256 + threadIdx.x) * 8;
    if (i >= n) return;
    float4 a = *(const float4*)(src + i);
    float4 b = *(const float4*)(src + i + 4);
    __hip_bfloat16 pk[8] = {
        __float2bfloat16(a.x), __float2bfloat16(a.y),
        __float2bfloat16(a.z), __float2bfloat16(a.w),
        __float2bfloat16(b.x), __float2bfloat16(b.y),
        __float2bfloat16(b.z), __float2bfloat16(b.w)};
    *(uint4*)(dst + i) = *(uint4*)pk;
}

// QKV GEMM: C = A[M,K] * W[N,K]^T, bf16, fp32 accum.
// PROVEN R5 SHAPE: 256 thr = 4 waves (2x2 of 64x64), 128x128 tile, BK=32,
// global_load_lds dwordx4 + chunk swizzle (2-way LDS reads).
// XCD cluster decode: linear-id%8 ~ XCD; each XCD owns 8 m-tiles x 4 n-tiles
// x 3 z -> A fetched 2x (16 MB) + W 4x (12 MB) instead of A 8x (64 MB, the
// R7-measured 68 MB FETCH). Working set/XCD ~3 MB < 4 MiB L2.
// z<2 fuses per-head l2norm (head width 64 = wave n-extent, 4 shfl_xor).
__global__ __launch_bounds__(256) void gemm_qkv(
    const __hip_bfloat16* __restrict__ A,
    const __hip_bfloat16* __restrict__ W0,
    const __hip_bfloat16* __restrict__ W1,
    const __hip_bfloat16* __restrict__ W2,
    __hip_bfloat16* __restrict__ C0,
    __hip_bfloat16* __restrict__ C1,
    __hip_bfloat16* __restrict__ C2,
    int M, int N, int K)
{
    // cluster decode (768 blocks): xcd = lid&7 -> (m-group 0..3, n-group 0..1)
    const int lid   = blockIdx.x + 8 * blockIdx.y + 256 * blockIdx.z;
    const int xcd   = lid & 7;
    const int s     = lid >> 3;          // 0..95
    const int m_loc = s & 7;
    const int rest  = s >> 3;            // 0..11
    const int n_loc = rest & 3;
    const int z     = rest >> 2;         // 0..2

    const __hip_bfloat16* W = (z == 0) ? W0 : (z == 1 ? W1 : W2);
    __hip_bfloat16* C = (z == 0) ? C0 : (z == 1 ? C1 : C2);

    const int m0 = ((xcd & 3) * 8 + m_loc) * 128;
    const int n0 = ((xcd >> 2) * 4 + n_loc) * 128;

    __shared__ __hip_bfloat16 As[128 * 32];
    __shared__ __hip_bfloat16 Bs[128 * 32];

    const int t    = threadIdx.x;
    const int lane = t & 63;
    const int wv   = t >> 6;

    // staging: wave wv covers rows [wv*32, wv*32+32), 2 insts of 16 rows each
    const int gc   = ((lane & 3) - (lane >> 3)) & 3;   // swizzled global chunk
    const int srow = wv * 32 + (lane >> 2);
    const __hip_bfloat16* Ag = A + (size_t)(m0 + srow) * K + gc * 8;
    const __hip_bfloat16* Wg = W + (size_t)(n0 + srow) * K + gc * 8;
    const size_t row16 = (size_t)16 * K;
    __hip_bfloat16* AsD0 = &As[(wv * 32) * 32];
    __hip_bfloat16* AsD1 = &As[(wv * 32 + 16) * 32];
    __hip_bfloat16* BsD0 = &Bs[(wv * 32) * 32];
    __hip_bfloat16* BsD1 = &Bs[(wv * 32 + 16) * 32];

    const int wm   = (wv >> 1) * 64;
    const int wn   = (wv & 1) * 64;
    const int lrow = lane & 15;
    const int quad = lane >> 4;
    const int slot = ((quad + (lrow >> 1)) & 3) * 8;   // swizzled read slot

    f32x4 acc[4][4];
#pragma unroll
    for (int i = 0; i < 4; i++)
#pragma unroll
        for (int j = 0; j < 4; j++)
            acc[i][j] = (f32x4){0.f, 0.f, 0.f, 0.f};

    for (int k0 = 0; k0 < K; k0 += 32) {
        gld_lds16(Ag + k0,         AsD0);
        gld_lds16(Ag + k0 + row16, AsD1);
        gld_lds16(Wg + k0,         BsD0);
        gld_lds16(Wg + k0 + row16, BsD1);
        __syncthreads();

        bf16x8 af[4], bfv[4];
#pragma unroll
        for (int mi = 0; mi < 4; mi++)
            af[mi] = *(const bf16x8*)&As[(wm + mi * 16 + lrow) * 32 + slot];
#pragma unroll
        for (int ni = 0; ni < 4; ni++)
            bfv[ni] = *(const bf16x8*)&Bs[(wn + ni * 16 + lrow) * 32 + slot];
#pragma unroll
        for (int mi = 0; mi < 4; mi++)
#pragma unroll
            for (int ni = 0; ni < 4; ni++)
                acc[mi][ni] = __builtin_amdgcn_mfma_f32_16x16x32_bf16(
                    af[mi], bfv[ni], acc[mi][ni], 0, 0, 0);
        __syncthreads();
    }

    // fused per-head l2norm for Q,K (z<2): head = the wave's 64-col extent
    if (z != 2) {
#pragma unroll
        for (int mi = 0; mi < 4; mi++) {
#pragma unroll
            for (int rr = 0; rr < 4; rr++) {
                float ss = 0.f;
#pragma unroll
                for (int ni = 0; ni < 4; ni++)
                    ss += acc[mi][ni][rr] * acc[mi][ni][rr];
                ss += __shfl_xor(ss, 1);
                ss += __shfl_xor(ss, 2);
                ss += __shfl_xor(ss, 4);
                ss += __shfl_xor(ss, 8);
                float inv = 1.0f / fmaxf(sqrtf(ss), 1e-6f);
#pragma unroll
                for (int ni = 0; ni < 4; ni++)
                    acc[mi][ni][rr] *= inv;
            }
        }
    }

    // epilogue: C/D layout col=lane&15, row=quad*4+reg  [verified m89/m91]
#pragma unroll
    for (int mi = 0; mi < 4; mi++) {
#pragma unroll
        for (int rr = 0; rr < 4; rr++) {
            int row = m0 + wm + mi * 16 + quad * 4 + rr;
            __hip_bfloat16* Crow = C + (size_t)row * N + n0 + wn + lrow;
#pragma unroll
            for (int ni = 0; ni < 4; ni++)
                Crow[ni * 16] = __float2bfloat16(acc[mi][ni][rr]);
        }
    }
}

// O-projection GEMM: 64x128 tile, 4 waves (2x2 of 32x64), fp32 C output.
// Same XCD cluster decode: each XCD owns 16 m-tiles x 4 n-tiles.
__global__ __launch_bounds__(256) void gemm_o(
    const __hip_bfloat16* __restrict__ A,
    const __hip_bfloat16* __restrict__ W,
    float* __restrict__ C,
    int M, int N, int K)
{
    const int lid   = blockIdx.x + 8 * blockIdx.y;   // 0..511
    const int xcd   = lid & 7;
    const int s     = lid >> 3;                      // 0..63
    const int m_loc = s & 15;
    const int n_loc = s >> 4;                        // 0..3

    const int m0 = ((xcd & 3) * 16 + m_loc) * 64;
    const int n0 = ((xcd >> 2) * 4 + n_loc) * 128;

    __shared__ __hip_bfloat16 As[64 * 32];
    __shared__ __hip_bfloat16 Bs[128 * 32];

    const int t    = threadIdx.x;
    const int lane = t & 63;
    const int wv   = t >> 6;

    const int gc    = ((lane & 3) - (lane >> 3)) & 3;
    const int srowA = wv * 16 + (lane >> 2);
    const int srowB = wv * 32 + (lane >> 2);
    const __hip_bfloat16* Ag = A + (size_t)(m0 + srowA) * K + gc * 8;
    const __hip_bfloat16* Wg = W + (size_t)(n0 + srowB) * K + gc * 8;
    const size_t row16 = (size_t)16 * K;
    __hip_bfloat16* AsD0 = &As[(wv * 16) * 32];
    __hip_bfloat16* BsD0 = &Bs[(wv * 32) * 32];
    __hip_bfloat16* BsD1 = &Bs[(wv * 32 + 16) * 32];

    const int wm   = (wv >> 1) * 32;
    const int wn   = (wv & 1) * 64;
    const int lrow = lane & 15;
    const int quad = lane >> 4;
    const int slot = ((quad + (lrow >> 1)) & 3) * 8;

    f32x4 acc[2][4];
#pragma unroll
    for (int i = 0; i < 2; i++)
#pragma unroll
        for (int j = 0; j < 4; j++)
            acc[i][j] = (f32x4){0.f, 0.f, 0.f, 0.f};

    for (int k0 = 0; k0 < K; k0 += 32) {
        gld_lds16(Ag + k0, AsD0);
        gld_lds16(Wg + k0,         BsD0);
        gld_lds16(Wg + k0 + row16, BsD1);
        __syncthreads();

        bf16x8 af[2], bfv[4];
#pragma unroll
        for (int mi = 0; mi < 2; mi++)
            af[mi] = *(const bf16x8*)&As[(wm + mi * 16 + lrow) * 32 + slot];
#pragma unroll
        for (int ni = 0; ni < 4; ni++)
            bfv[ni] = *(const bf16x8*)&Bs[(wn + ni * 16 + lrow) * 32 + slot];
#pragma unroll
        for (int mi = 0; mi < 2; mi++)
#pragma unroll
            for (int ni = 0; ni < 4; ni++)
                acc[mi][ni] = __builtin_amdgcn_mfma_f32_16x16x32_bf16(
                    af[mi], bfv[ni], acc[mi][ni], 0, 0, 0);
        __syncthreads();
    }

#pragma unroll
    for (int mi = 0; mi < 2; mi++) {
#pragma unroll
        for (int rr = 0; rr < 4; rr++) {
            int row = m0 + wm + mi * 16 + quad * 4 + rr;
            float* Crow = C + (size_t)row * N + n0 + wn + lrow;
#pragma unroll
            for (int ni = 0; ni < 4; ni++)
                Crow[ni * 16] = acc[mi][ni][rr];
        }
    }
}

// MFMA sliding-window attention. Block = 256 thr = one (b,h) x 64-query tile.
// K staged via global_load_lds into unpadded stride-64 Ks with 8-chunk
// rotation swizzle: LDS slot s at row r holds global chunk (s-r)&7; read
// slot for chunk c is (c+r)&7 -> 2-way banks (free) on b128 frag reads.
// LDS = 49 KB -> 3 blocks/CU.
__global__ __launch_bounds__(256) void attn_kernel(
    const __hip_bfloat16* __restrict__ Q,
    const __hip_bfloat16* __restrict__ K,
    const __hip_bfloat16* __restrict__ V,
    __hip_bfloat16* __restrict__ O)
{
    const int i0 = blockIdx.x * 64;
    const int h  = blockIdx.y;
    const int b  = blockIdx.z;

    __shared__ __hip_bfloat16 Ks[192 * 64];   // keys band (swizzled); P overlay later
    __shared__ __hip_bfloat16 Vt[64 * 200];   // V^T, swizzled key blocks

    const size_t base = ((size_t)b * T_SEQ) * DMODEL + h * HDIM;
    const int t    = threadIdx.x;
    const int lane = t & 63;
    const int w    = t >> 6;

    // K staging via DMA: 6 insts/wave, each 8 rows x 64 elems
    {
        const int drow = lane >> 3, sl = lane & 7;
#pragma unroll
        for (int inst = 0; inst < 6; inst++) {
            int r0 = w * 48 + inst * 8;
            int r  = r0 + drow;
            int gcx = (sl - r) & 7;
            int j  = min(i0 + r, T_SEQ - 1);
            gld_lds16(K + base + (size_t)j * DMODEL + gcx * 8, &Ks[r0 * 64]);
        }
    }
    // V staging: 8x8 register transpose, swizzled b128 writes
    for (int task = t; task < 192; task += 256) {
        int c  = task & 7;            // dim chunk
        int r0 = (task >> 3) * 8;     // key block start
        int b0 = task >> 3;           // key block index (0..23)
        unsigned short m[8][8];
#pragma unroll
        for (int i = 0; i < 8; i++) {
            int j = min(i0 + r0 + i, T_SEQ - 1);
            uint4 u = *(const uint4*)(V + base + (size_t)j * DMODEL + c * 8);
            unsigned short tmp[8];
            *(uint4*)tmp = u;
#pragma unroll
            for (int e = 0; e < 8; e++) m[e][i] = tmp[e];
        }
#pragma unroll
        for (int e = 0; e < 8; e++) {
            int d  = c * 8 + e;
            int sg = (b0 & ~7) | ((b0 + (d >> 3)) & 7);
            *(uint4*)&Vt[d * 200 + sg * 8] = *(uint4*)m[e];
        }
    }
    // zero slot 24 (tail keys; P is zero there but data must be finite)
    for (int task = t; task < 64; task += 256) {
        uint4 zz = {0, 0, 0, 0};
        *(uint4*)&Vt[task * 200 + 192] = zz;
    }
    __syncthreads();

    const int col  = lane & 15;
    const int quad = lane >> 4;
    const float slope = exp2f(-8.0f * (float)h / 15.0f);

    const __hip_bfloat16* qp = Q + base + (size_t)(i0 + w * 16 + col) * DMODEL + quad * 8;
    bf16x8 qf0 = *(const bf16x8*)(qp);
    bf16x8 qf1 = *(const bf16x8*)(qp + 32);

    f32x4 sc[9];
#pragma unroll
    for (int kt = 0; kt < 9; kt++) {
        sc[kt] = (f32x4){0.f, 0.f, 0.f, 0.f};
        int r = w * 16 + kt * 16 + col;
        bf16x8 kb0 = *(const bf16x8*)&Ks[r * 64 + ((quad     + r) & 7) * 8];
        bf16x8 kb1 = *(const bf16x8*)&Ks[r * 64 + ((quad + 4 + r) & 7) * 8];
        sc[kt] = __builtin_amdgcn_mfma_f32_16x16x32_bf16(qf0, kb0, sc[kt], 0, 0, 0);
        sc[kt] = __builtin_amdgcn_mfma_f32_16x16x32_bf16(qf1, kb1, sc[kt], 0, 0, 0);
    }

    float mx[4] = {-3e38f, -3e38f, -3e38f, -3e38f};
#pragma unroll
    for (int kt = 0; kt < 9; kt++) {
#pragma unroll
        for (int r = 0; r < 4; r++) {
            int ql  = quad * 4 + r;
            int rel = kt * 16 + col - ql;
            int ka  = i0 + w * 16 + kt * 16 + col;
            bool valid = (rel >= 0) && (rel < WINDOW) && (ka < T_SEQ);
            float v = valid ? (sc[kt][r] - (float)rel * slope) : -1e30f;
            sc[kt][r] = v;
            mx[r] = fmaxf(mx[r], v);
        }
    }
#pragma unroll
    for (int r = 0; r < 4; r++) {
        mx[r] = fmaxf(mx[r], __shfl_xor(mx[r], 1));
        mx[r] = fmaxf(mx[r], __shfl_xor(mx[r], 2));
        mx[r] = fmaxf(mx[r], __shfl_xor(mx[r], 4));
        mx[r] = fmaxf(mx[r], __shfl_xor(mx[r], 8));
    }
    float sm[4] = {0.f, 0.f, 0.f, 0.f};
#pragma unroll
    for (int kt = 0; kt < 9; kt++) {
#pragma unroll
        for (int r = 0; r < 4; r++) {
            float e = __expf(sc[kt][r] - mx[r]);
            sc[kt][r] = e;
            sm[r] += e;
        }
    }
#pragma unroll
    for (int r = 0; r < 4; r++) {
        sm[r] += __shfl_xor(sm[r], 1);
        sm[r] += __shfl_xor(sm[r], 2);
        sm[r] += __shfl_xor(sm[r], 4);
        sm[r] += __shfl_xor(sm[r], 8);
        sm[r] = 1.0f / sm[r];
    }

    // all Ks reads done -> overlay P (per-wave region, stride 168)
    __syncthreads();
    __hip_bfloat16* Ps = Ks + w * (16 * 168);
#pragma unroll
    for (int kt = 0; kt < 9; kt++)
#pragma unroll
        for (int r = 0; r < 4; r++)
            Ps[(quad * 4 + r) * 168 + kt * 16 + col] = __float2bfloat16(sc[kt][r] * sm[r]);
#pragma unroll
    for (int i = 0; i < 4; i++)
        Ps[(lane & 15) * 168 + 144 + quad * 4 + i] = __float2bfloat16(0.f);
    __syncthreads();

    // PV: A = P[q][key], B = Vt[dim][key] (swizzled slots)
    f32x4 o[4];
#pragma unroll
    for (int nd = 0; nd < 4; nd++) o[nd] = (f32x4){0.f, 0.f, 0.f, 0.f};
#pragma unroll
    for (int kc = 0; kc < 5; kc++) {
        bf16x8 pf = *(const bf16x8*)&Ps[col * 168 + kc * 32 + quad * 8];
        int bblk = w * 2 + kc * 4 + quad;
#pragma unroll
        for (int nd = 0; nd < 4; nd++) {
            int d  = nd * 16 + col;
            int sg = (bblk < 24) ? ((bblk & ~7) | ((bblk + (d >> 3)) & 7)) : 24;
            bf16x8 vf = *(const bf16x8*)&Vt[d * 200 + sg * 8];
            o[nd] = __builtin_amdgcn_mfma_f32_16x16x32_bf16(pf, vf, o[nd], 0, 0, 0);
        }
    }

#pragma unroll
    for (int r = 0; r < 4; r++) {
        __hip_bfloat16* op = O + base + (size_t)(i0 + w * 16 + quad * 4 + r) * DMODEL + col;
#pragma unroll
        for (int nd = 0; nd < 4; nd++)
            op[nd * 16] = __float2bfloat16(o[nd][r]);
    }
}

extern "C" void kernel_launch(void* const* d_in, const int* in_sizes, int n_in,
                              void* d_out, int out_size, void* d_ws, size_t ws_size,
                              hipStream_t stream)
{
    const float* x  = (const float*)d_in[0];
    const float* Wq = (const float*)d_in[1];
    const float* Wk = (const float*)d_in[2];
    const float* Wv = (const float*)d_in[3];
    const float* Wo = (const float*)d_in[4];
    float* out = (float*)d_out;

    const size_t MT = (size_t)BATCH * T_SEQ;          // 4096 rows
    __hip_bfloat16* Qw = (__hip_bfloat16*)d_ws;       // 8 MB each (bf16)
    __hip_bfloat16* Kw = Qw + MT * DMODEL;
    __hip_bfloat16* Vw = Kw + MT * DMODEL;
    __hip_bfloat16* XA = Vw + MT * DMODEL;            // xb (pre-attn) / AO (post-attn)
    __hip_bfloat16* Wb = XA + MT * DMODEL;            // 4 x 1M bf16 weights

    cvt_kernel<<<dim3(2048, 5), 256, 0, stream>>>(x, Wq, Wk, Wv, Wo, XA, Wb);

    dim3 g1(DMODEL / 128, MT / 128, 3);
    gemm_qkv<<<g1, 256, 0, stream>>>(
        XA, Wb, Wb + 1024 * 1024, Wb + 2 * 1024 * 1024,
        Qw, Kw, Vw, (int)MT, DMODEL, DMODEL);

    dim3 g2(T_SEQ / 64, NHEADS, BATCH);
    attn_kernel<<<g2, 256, 0, stream>>>(Qw, Kw, Vw, XA);

    dim3 g3(DMODEL / 128, MT / 64, 1);
    gemm_o<<<g3, 256, 0, stream>>>(
        XA, Wb + 3 * 1024 * 1024, out, (int)MT, DMODEL, DMODEL);
}

// Round 10
// 150.939 us; speedup vs baseline: 1.2262x; 1.0188x over previous
//
#include <hip/hip_runtime.h>
#include <hip/hip_bf16.h>

#define T_SEQ   2048
#define BATCH   2
#define DMODEL  1024
#define NHEADS  16
#define HDIM    64
#define WINDOW  128

typedef __attribute__((ext_vector_type(8))) short bf16x8;
typedef __attribute__((ext_vector_type(4))) float f32x4;

// async global->LDS 16B per lane; LDS dest = wave-uniform base + lane*16
__device__ inline void gld_lds16(const __hip_bfloat16* g, __hip_bfloat16* l) {
    __builtin_amdgcn_global_load_lds(
        (const __attribute__((address_space(1))) unsigned int*)g,
        (__attribute__((address_space(3))) unsigned int*)l, 16, 0, 0);
}

// fp32 -> bf16 bulk convert, exact 1D grid: lid<2048 -> x (4M elems),
// else 512 blocks per weight slot (1M each).
__global__ __launch_bounds__(256) void cvt_kernel(
    const float* __restrict__ x,  const float* __restrict__ Wq,
    const float* __restrict__ Wk, const float* __restrict__ Wv,
    const float* __restrict__ Wo,
    __hip_bfloat16* __restrict__ xb, __hip_bfloat16* __restrict__ Wb)
{
    const int lid = blockIdx.x;
    const float* src;
    __hip_bfloat16* dst;
    int blk;
    if (lid < 2048) { src = x; dst = xb; blk = lid; }
    else {
        int slot = (lid - 2048) >> 9;           // 0..3
        blk = (lid - 2048) & 511;
        src = (slot == 0) ? Wq : (slot == 1) ? Wk : (slot == 2) ? Wv : Wo;
        dst = Wb + (size_t)slot * 1024 * 1024;
    }
    int i = (blk * 256 + threadIdx.x) * 8;
    float4 a = *(const float4*)(src + i);
    float4 b = *(const float4*)(src + i + 4);
    __hip_bfloat16 pk[8] = {
        __float2bfloat16(a.x), __float2bfloat16(a.y),
        __float2bfloat16(a.z), __float2bfloat16(a.w),
        __float2bfloat16(b.x), __float2bfloat16(b.y),
        __float2bfloat16(b.z), __float2bfloat16(b.w)};
    *(uint4*)(dst + i) = *(uint4*)pk;
}

// QKV GEMM: C = A[M,K] * W[N,K]^T, bf16, fp32 accum. PROVEN R5 shape:
// 256 thr = 4 waves (2x2 of 64x64), 128x128 tile, BK=32, global_load_lds
// dwordx4 + chunk swizzle (2-way LDS reads). XCD cluster decode for L2
// locality. z<2 fuses per-head l2norm.
__global__ __launch_bounds__(256) void gemm_qkv(
    const __hip_bfloat16* __restrict__ A,
    const __hip_bfloat16* __restrict__ W0,
    const __hip_bfloat16* __restrict__ W1,
    const __hip_bfloat16* __restrict__ W2,
    __hip_bfloat16* __restrict__ C0,
    __hip_bfloat16* __restrict__ C1,
    __hip_bfloat16* __restrict__ C2,
    int M, int N, int K)
{
    const int lid   = blockIdx.x + 8 * blockIdx.y + 256 * blockIdx.z;
    const int xcd   = lid & 7;
    const int s     = lid >> 3;
    const int m_loc = s & 7;
    const int rest  = s >> 3;
    const int n_loc = rest & 3;
    const int z     = rest >> 2;

    const __hip_bfloat16* W = (z == 0) ? W0 : (z == 1 ? W1 : W2);
    __hip_bfloat16* C = (z == 0) ? C0 : (z == 1 ? C1 : C2);

    const int m0 = ((xcd & 3) * 8 + m_loc) * 128;
    const int n0 = ((xcd >> 2) * 4 + n_loc) * 128;

    __shared__ __hip_bfloat16 As[128 * 32];
    __shared__ __hip_bfloat16 Bs[128 * 32];

    const int t    = threadIdx.x;
    const int lane = t & 63;
    const int wv   = t >> 6;

    const int gc   = ((lane & 3) - (lane >> 3)) & 3;
    const int srow = wv * 32 + (lane >> 2);
    const __hip_bfloat16* Ag = A + (size_t)(m0 + srow) * K + gc * 8;
    const __hip_bfloat16* Wg = W + (size_t)(n0 + srow) * K + gc * 8;
    const size_t row16 = (size_t)16 * K;
    __hip_bfloat16* AsD0 = &As[(wv * 32) * 32];
    __hip_bfloat16* AsD1 = &As[(wv * 32 + 16) * 32];
    __hip_bfloat16* BsD0 = &Bs[(wv * 32) * 32];
    __hip_bfloat16* BsD1 = &Bs[(wv * 32 + 16) * 32];

    const int wm   = (wv >> 1) * 64;
    const int wn   = (wv & 1) * 64;
    const int lrow = lane & 15;
    const int quad = lane >> 4;
    const int slot = ((quad + (lrow >> 1)) & 3) * 8;

    f32x4 acc[4][4];
#pragma unroll
    for (int i = 0; i < 4; i++)
#pragma unroll
        for (int j = 0; j < 4; j++)
            acc[i][j] = (f32x4){0.f, 0.f, 0.f, 0.f};

    for (int k0 = 0; k0 < K; k0 += 32) {
        gld_lds16(Ag + k0,         AsD0);
        gld_lds16(Ag + k0 + row16, AsD1);
        gld_lds16(Wg + k0,         BsD0);
        gld_lds16(Wg + k0 + row16, BsD1);
        __syncthreads();

        bf16x8 af[4], bfv[4];
#pragma unroll
        for (int mi = 0; mi < 4; mi++)
            af[mi] = *(const bf16x8*)&As[(wm + mi * 16 + lrow) * 32 + slot];
#pragma unroll
        for (int ni = 0; ni < 4; ni++)
            bfv[ni] = *(const bf16x8*)&Bs[(wn + ni * 16 + lrow) * 32 + slot];
#pragma unroll
        for (int mi = 0; mi < 4; mi++)
#pragma unroll
            for (int ni = 0; ni < 4; ni++)
                acc[mi][ni] = __builtin_amdgcn_mfma_f32_16x16x32_bf16(
                    af[mi], bfv[ni], acc[mi][ni], 0, 0, 0);
        __syncthreads();
    }

    if (z != 2) {
#pragma unroll
        for (int mi = 0; mi < 4; mi++) {
#pragma unroll
            for (int rr = 0; rr < 4; rr++) {
                float ss = 0.f;
#pragma unroll
                for (int ni = 0; ni < 4; ni++)
                    ss += acc[mi][ni][rr] * acc[mi][ni][rr];
                ss += __shfl_xor(ss, 1);
                ss += __shfl_xor(ss, 2);
                ss += __shfl_xor(ss, 4);
                ss += __shfl_xor(ss, 8);
                float inv = 1.0f / fmaxf(sqrtf(ss), 1e-6f);
#pragma unroll
                for (int ni = 0; ni < 4; ni++)
                    acc[mi][ni][rr] *= inv;
            }
        }
    }

#pragma unroll
    for (int mi = 0; mi < 4; mi++) {
#pragma unroll
        for (int rr = 0; rr < 4; rr++) {
            int row = m0 + wm + mi * 16 + quad * 4 + rr;
            __hip_bfloat16* Crow = C + (size_t)row * N + n0 + wn + lrow;
#pragma unroll
            for (int ni = 0; ni < 4; ni++)
                Crow[ni * 16] = __float2bfloat16(acc[mi][ni][rr]);
        }
    }
}

// O-projection GEMM: 64x128 tile, 4 waves, fp32 C. XCD cluster decode.
__global__ __launch_bounds__(256) void gemm_o(
    const __hip_bfloat16* __restrict__ A,
    const __hip_bfloat16* __restrict__ W,
    float* __restrict__ C,
    int M, int N, int K)
{
    const int lid   = blockIdx.x + 8 * blockIdx.y;
    const int xcd   = lid & 7;
    const int s     = lid >> 3;
    const int m_loc = s & 15;
    const int n_loc = s >> 4;

    const int m0 = ((xcd & 3) * 16 + m_loc) * 64;
    const int n0 = ((xcd >> 2) * 4 + n_loc) * 128;

    __shared__ __hip_bfloat16 As[64 * 32];
    __shared__ __hip_bfloat16 Bs[128 * 32];

    const int t    = threadIdx.x;
    const int lane = t & 63;
    const int wv   = t >> 6;

    const int gc    = ((lane & 3) - (lane >> 3)) & 3;
    const int srowA = wv * 16 + (lane >> 2);
    const int srowB = wv * 32 + (lane >> 2);
    const __hip_bfloat16* Ag = A + (size_t)(m0 + srowA) * K + gc * 8;
    const __hip_bfloat16* Wg = W + (size_t)(n0 + srowB) * K + gc * 8;
    const size_t row16 = (size_t)16 * K;
    __hip_bfloat16* AsD0 = &As[(wv * 16) * 32];
    __hip_bfloat16* BsD0 = &Bs[(wv * 32) * 32];
    __hip_bfloat16* BsD1 = &Bs[(wv * 32 + 16) * 32];

    const int wm   = (wv >> 1) * 32;
    const int wn   = (wv & 1) * 64;
    const int lrow = lane & 15;
    const int quad = lane >> 4;
    const int slot = ((quad + (lrow >> 1)) & 3) * 8;

    f32x4 acc[2][4];
#pragma unroll
    for (int i = 0; i < 2; i++)
#pragma unroll
        for (int j = 0; j < 4; j++)
            acc[i][j] = (f32x4){0.f, 0.f, 0.f, 0.f};

    for (int k0 = 0; k0 < K; k0 += 32) {
        gld_lds16(Ag + k0, AsD0);
        gld_lds16(Wg + k0,         BsD0);
        gld_lds16(Wg + k0 + row16, BsD1);
        __syncthreads();

        bf16x8 af[2], bfv[4];
#pragma unroll
        for (int mi = 0; mi < 2; mi++)
            af[mi] = *(const bf16x8*)&As[(wm + mi * 16 + lrow) * 32 + slot];
#pragma unroll
        for (int ni = 0; ni < 4; ni++)
            bfv[ni] = *(const bf16x8*)&Bs[(wn + ni * 16 + lrow) * 32 + slot];
#pragma unroll
        for (int mi = 0; mi < 2; mi++)
#pragma unroll
            for (int ni = 0; ni < 4; ni++)
                acc[mi][ni] = __builtin_amdgcn_mfma_f32_16x16x32_bf16(
                    af[mi], bfv[ni], acc[mi][ni], 0, 0, 0);
        __syncthreads();
    }

#pragma unroll
    for (int mi = 0; mi < 2; mi++) {
#pragma unroll
        for (int rr = 0; rr < 4; rr++) {
            int row = m0 + wm + mi * 16 + quad * 4 + rr;
            float* Crow = C + (size_t)row * N + n0 + wn + lrow;
#pragma unroll
            for (int ni = 0; ni < 4; ni++)
                Crow[ni * 16] = acc[mi][ni][rr];
        }
    }
}

// MFMA sliding-window attention, 128-query blocks (8 waves, 512 thr).
// Grid 512 = exactly 2 blocks/CU -> one balanced round (was 1024 @ 3/CU =
// full round + 1/3-occupancy tail). LDS 75 KB: KsP union (Ks 256x64 = 32 KB
// phase 1 / P 8x16x168 = 42 KB phase 2) + Vt 64x264 = 33 KB.
__global__ __launch_bounds__(512) void attn_kernel(
    const __hip_bfloat16* __restrict__ Q,
    const __hip_bfloat16* __restrict__ K,
    const __hip_bfloat16* __restrict__ V,
    __hip_bfloat16* __restrict__ O)
{
    const int qb = blockIdx.x * 128;
    const int h  = blockIdx.y;
    const int b  = blockIdx.z;

    __shared__ __hip_bfloat16 KsP[8 * 16 * 168];  // >= 256*64; P overlay later
    __shared__ __hip_bfloat16 Vt[64 * 264];       // V^T, swizzled key blocks

    const size_t base = ((size_t)b * T_SEQ) * DMODEL + h * HDIM;
    const int t    = threadIdx.x;
    const int lane = t & 63;
    const int w    = t >> 6;                      // wave 0..7

    // K staging via DMA: wave w covers rows [w*32, w*32+32), 4 insts of 8 rows.
    // 8-chunk rotation: LDS slot s at row r holds global chunk (s-r)&7.
    {
        const int drow = lane >> 3, sl = lane & 7;
#pragma unroll
        for (int inst = 0; inst < 4; inst++) {
            int r0 = w * 32 + inst * 8;
            int r  = r0 + drow;
            int gcx = (sl - r) & 7;
            int j  = min(qb + r, T_SEQ - 1);
            gld_lds16(K + base + (size_t)j * DMODEL + gcx * 8, &KsP[r0 * 64]);
        }
    }
    // V staging: 256 tasks (dim-chunk c, key-block b0), 8x8 register transpose,
    // swizzled b128 writes: sg = (b0&~7)|((b0+c)&7)  (d>>3 == c).
    if (t < 256) {
        int c  = t & 7;
        int b0 = t >> 3;              // 0..31
        int sg = (b0 & ~7) | ((b0 + c) & 7);
        unsigned short m[8][8];
#pragma unroll
        for (int i = 0; i < 8; i++) {
            int j = min(qb + b0 * 8 + i, T_SEQ - 1);
            uint4 u = *(const uint4*)(V + base + (size_t)j * DMODEL + c * 8);
            unsigned short tmp[8];
            *(uint4*)tmp = u;
#pragma unroll
            for (int e = 0; e < 8; e++) m[e][i] = tmp[e];
        }
#pragma unroll
        for (int e = 0; e < 8; e++)
            *(uint4*)&Vt[(c * 8 + e) * 264 + sg * 8] = *(uint4*)m[e];
    }
    // zero tail slot 32 (keys >= 256; P is zero there but data must be finite)
    if (t < 64) {
        uint4 zz = {0, 0, 0, 0};
        *(uint4*)&Vt[t * 264 + 256] = zz;
    }
    __syncthreads();

    const int col  = lane & 15;
    const int quad = lane >> 4;
    const float slope = exp2f(-8.0f * (float)h / 15.0f);

    const __hip_bfloat16* qp = Q + base + (size_t)(qb + w * 16 + col) * DMODEL + quad * 8;
    bf16x8 qf0 = *(const bf16x8*)(qp);
    bf16x8 qf1 = *(const bf16x8*)(qp + 32);

    f32x4 sc[9];
#pragma unroll
    for (int kt = 0; kt < 9; kt++) {
        sc[kt] = (f32x4){0.f, 0.f, 0.f, 0.f};
        int r = w * 16 + kt * 16 + col;
        bf16x8 kb0 = *(const bf16x8*)&KsP[r * 64 + ((quad     + r) & 7) * 8];
        bf16x8 kb1 = *(const bf16x8*)&KsP[r * 64 + ((quad + 4 + r) & 7) * 8];
        sc[kt] = __builtin_amdgcn_mfma_f32_16x16x32_bf16(qf0, kb0, sc[kt], 0, 0, 0);
        sc[kt] = __builtin_amdgcn_mfma_f32_16x16x32_bf16(qf1, kb1, sc[kt], 0, 0, 0);
    }

    float mx[4] = {-3e38f, -3e38f, -3e38f, -3e38f};
#pragma unroll
    for (int kt = 0; kt < 9; kt++) {
#pragma unroll
        for (int r = 0; r < 4; r++) {
            int ql  = quad * 4 + r;
            int rel = kt * 16 + col - ql;
            int ka  = qb + w * 16 + kt * 16 + col;
            bool valid = (rel >= 0) && (rel < WINDOW) && (ka < T_SEQ);
            float v = valid ? (sc[kt][r] - (float)rel * slope) : -1e30f;
            sc[kt][r] = v;
            mx[r] = fmaxf(mx[r], v);
        }
    }
#pragma unroll
    for (int r = 0; r < 4; r++) {
        mx[r] = fmaxf(mx[r], __shfl_xor(mx[r], 1));
        mx[r] = fmaxf(mx[r], __shfl_xor(mx[r], 2));
        mx[r] = fmaxf(mx[r], __shfl_xor(mx[r], 4));
        mx[r] = fmaxf(mx[r], __shfl_xor(mx[r], 8));
    }
    float sm[4] = {0.f, 0.f, 0.f, 0.f};
#pragma unroll
    for (int kt = 0; kt < 9; kt++) {
#pragma unroll
        for (int r = 0; r < 4; r++) {
            float e = __expf(sc[kt][r] - mx[r]);
            sc[kt][r] = e;
            sm[r] += e;
        }
    }
#pragma unroll
    for (int r = 0; r < 4; r++) {
        sm[r] += __shfl_xor(sm[r], 1);
        sm[r] += __shfl_xor(sm[r], 2);
        sm[r] += __shfl_xor(sm[r], 4);
        sm[r] += __shfl_xor(sm[r], 8);
        sm[r] = 1.0f / sm[r];
    }

    // all Ks reads done -> overlay P (per-wave region, stride 168)
    __syncthreads();
    __hip_bfloat16* Ps = KsP + w * (16 * 168);
#pragma unroll
    for (int kt = 0; kt < 9; kt++)
#pragma unroll
        for (int r = 0; r < 4; r++)
            Ps[(quad * 4 + r) * 168 + kt * 16 + col] = __float2bfloat16(sc[kt][r] * sm[r]);
#pragma unroll
    for (int i = 0; i < 4; i++)
        Ps[(lane & 15) * 168 + 144 + quad * 4 + i] = __float2bfloat16(0.f);
    __syncthreads();

    // PV: A = P[q][key], B = Vt[dim][key] (swizzled slots)
    f32x4 o[4];
#pragma unroll
    for (int nd = 0; nd < 4; nd++) o[nd] = (f32x4){0.f, 0.f, 0.f, 0.f};
#pragma unroll
    for (int kc = 0; kc < 5; kc++) {
        bf16x8 pf = *(const bf16x8*)&Ps[col * 168 + kc * 32 + quad * 8];
        int bblk = w * 2 + kc * 4 + quad;
#pragma unroll
        for (int nd = 0; nd < 4; nd++) {
            int d  = nd * 16 + col;
            int sg = (bblk < 32) ? ((bblk & ~7) | ((bblk + (d >> 3)) & 7)) : 32;
            bf16x8 vf = *(const bf16x8*)&Vt[d * 264 + sg * 8];
            o[nd] = __builtin_amdgcn_mfma_f32_16x16x32_bf16(pf, vf, o[nd], 0, 0, 0);
        }
    }

#pragma unroll
    for (int r = 0; r < 4; r++) {
        __hip_bfloat16* op = O + base + (size_t)(qb + w * 16 + quad * 4 + r) * DMODEL + col;
#pragma unroll
        for (int nd = 0; nd < 4; nd++)
            op[nd * 16] = __float2bfloat16(o[nd][r]);
    }
}

extern "C" void kernel_launch(void* const* d_in, const int* in_sizes, int n_in,
                              void* d_out, int out_size, void* d_ws, size_t ws_size,
                              hipStream_t stream)
{
    const float* x  = (const float*)d_in[0];
    const float* Wq = (const float*)d_in[1];
    const float* Wk = (const float*)d_in[2];
    const float* Wv = (const float*)d_in[3];
    const float* Wo = (const float*)d_in[4];
    float* out = (float*)d_out;

    const size_t MT = (size_t)BATCH * T_SEQ;          // 4096 rows
    __hip_bfloat16* Qw = (__hip_bfloat16*)d_ws;       // 8 MB each (bf16)
    __hip_bfloat16* Kw = Qw + MT * DMODEL;
    __hip_bfloat16* Vw = Kw + MT * DMODEL;
    __hip_bfloat16* XA = Vw + MT * DMODEL;            // xb (pre-attn) / AO (post-attn)
    __hip_bfloat16* Wb = XA + MT * DMODEL;            // 4 x 1M bf16 weights

    cvt_kernel<<<4096, 256, 0, stream>>>(x, Wq, Wk, Wv, Wo, XA, Wb);

    dim3 g1(DMODEL / 128, MT / 128, 3);
    gemm_qkv<<<g1, 256, 0, stream>>>(
        XA, Wb, Wb + 1024 * 1024, Wb + 2 * 1024 * 1024,
        Qw, Kw, Vw, (int)MT, DMODEL, DMODEL);

    dim3 g2(T_SEQ / 128, NHEADS, BATCH);
    attn_kernel<<<g2, 512, 0, stream>>>(Qw, Kw, Vw, XA);

    dim3 g3(DMODEL / 128, MT / 64, 1);
    gemm_o<<<g3, 256, 0, stream>>>(
        XA, Wb + 3 * 1024 * 1024, out, (int)MT, DMODEL, DMODEL);
}

// Round 11
// 143.568 us; speedup vs baseline: 1.2891x; 1.0513x over previous
//
#include <hip/hip_runtime.h>
#include <hip/hip_bf16.h>

#define T_SEQ   2048
#define BATCH   2
#define DMODEL  1024
#define NHEADS  16
#define HDIM    64
#define WINDOW  128

typedef __attribute__((ext_vector_type(8))) short bf16x8;
typedef __attribute__((ext_vector_type(4))) float f32x4;

// async global->LDS 16B per lane; LDS dest = wave-uniform base + lane*16
__device__ inline void gld_lds16(const __hip_bfloat16* g, __hip_bfloat16* l) {
    __builtin_amdgcn_global_load_lds(
        (const __attribute__((address_space(1))) unsigned int*)g,
        (__attribute__((address_space(3))) unsigned int*)l, 16, 0, 0);
}

// fp32 -> bf16 bulk convert, exact 1D grid: lid<2048 -> x (4M elems),
// else 512 blocks per weight slot (1M each).
__global__ __launch_bounds__(256) void cvt_kernel(
    const float* __restrict__ x,  const float* __restrict__ Wq,
    const float* __restrict__ Wk, const float* __restrict__ Wv,
    const float* __restrict__ Wo,
    __hip_bfloat16* __restrict__ xb, __hip_bfloat16* __restrict__ Wb)
{
    const int lid = blockIdx.x;
    const float* src;
    __hip_bfloat16* dst;
    int blk;
    if (lid < 2048) { src = x; dst = xb; blk = lid; }
    else {
        int slot = (lid - 2048) >> 9;           // 0..3
        blk = (lid - 2048) & 511;
        src = (slot == 0) ? Wq : (slot == 1) ? Wk : (slot == 2) ? Wv : Wo;
        dst = Wb + (size_t)slot * 1024 * 1024;
    }
    int i = (blk * 256 + threadIdx.x) * 8;
    float4 a = *(const float4*)(src + i);
    float4 b = *(const float4*)(src + i + 4);
    __hip_bfloat16 pk[8] = {
        __float2bfloat16(a.x), __float2bfloat16(a.y),
        __float2bfloat16(a.z), __float2bfloat16(a.w),
        __float2bfloat16(b.x), __float2bfloat16(b.y),
        __float2bfloat16(b.z), __float2bfloat16(b.w)};
    *(uint4*)(dst + i) = *(uint4*)pk;
}

// QKV GEMM: C = A[M,K] * W[N,K]^T, bf16, fp32 accum.
// R5 4-wave shape + BK=64: 128x128 tile, LDS 32 KB, 16 barriers (was 32).
// 8-chunk rotation swizzle: LDS slot s at row r holds global chunk (s-r)&7;
// read slot for chunk c at row r is (c+r)&7 (2-way banks on b128 = free —
// same pattern as the attn Ks staging, conflict-free since R8).
// XCD cluster decode for L2 locality; z<2 fuses per-head l2norm.
__global__ __launch_bounds__(256) void gemm_qkv(
    const __hip_bfloat16* __restrict__ A,
    const __hip_bfloat16* __restrict__ W0,
    const __hip_bfloat16* __restrict__ W1,
    const __hip_bfloat16* __restrict__ W2,
    __hip_bfloat16* __restrict__ C0,
    __hip_bfloat16* __restrict__ C1,
    __hip_bfloat16* __restrict__ C2,
    int M, int N, int K)
{
    const int lid   = blockIdx.x + 8 * blockIdx.y + 256 * blockIdx.z;
    const int xcd   = lid & 7;
    const int s     = lid >> 3;
    const int m_loc = s & 7;
    const int rest  = s >> 3;
    const int n_loc = rest & 3;
    const int z     = rest >> 2;

    const __hip_bfloat16* W = (z == 0) ? W0 : (z == 1 ? W1 : W2);
    __hip_bfloat16* C = (z == 0) ? C0 : (z == 1 ? C1 : C2);

    const int m0 = ((xcd & 3) * 8 + m_loc) * 128;
    const int n0 = ((xcd >> 2) * 4 + n_loc) * 128;

    __shared__ __hip_bfloat16 As[128 * 64];
    __shared__ __hip_bfloat16 Bs[128 * 64];

    const int t    = threadIdx.x;
    const int lane = t & 63;
    const int wv   = t >> 6;

    // staging: wave wv covers rows [wv*32, wv*32+32) of As and Bs,
    // 4 DMA insts each of 8 rows x 64 cols; lane fetches chunk (sl-row)&7.
    const int drow = lane >> 3;
    const int sl   = lane & 7;

    const int wm   = (wv >> 1) * 64;
    const int wn   = (wv & 1) * 64;
    const int lrow = lane & 15;
    const int quad = lane >> 4;

    f32x4 acc[4][4];
#pragma unroll
    for (int i = 0; i < 4; i++)
#pragma unroll
        for (int j = 0; j < 4; j++)
            acc[i][j] = (f32x4){0.f, 0.f, 0.f, 0.f};

    for (int k0 = 0; k0 < K; k0 += 64) {
#pragma unroll
        for (int inst = 0; inst < 4; inst++) {
            int r0 = wv * 32 + inst * 8;
            int r  = r0 + drow;
            int gcx = (sl - r) & 7;
            gld_lds16(A + (size_t)(m0 + r) * K + k0 + gcx * 8, &As[r0 * 64]);
            gld_lds16(W + (size_t)(n0 + r) * K + k0 + gcx * 8, &Bs[r0 * 64]);
        }
        __syncthreads();

#pragma unroll
        for (int kk = 0; kk < 2; kk++) {
            bf16x8 af[4], bfv[4];
#pragma unroll
            for (int mi = 0; mi < 4; mi++) {
                int r = wm + mi * 16 + lrow;
                af[mi] = *(const bf16x8*)&As[r * 64 + ((kk * 4 + quad + r) & 7) * 8];
            }
#pragma unroll
            for (int ni = 0; ni < 4; ni++) {
                int r = wn + ni * 16 + lrow;
                bfv[ni] = *(const bf16x8*)&Bs[r * 64 + ((kk * 4 + quad + r) & 7) * 8];
            }
#pragma unroll
            for (int mi = 0; mi < 4; mi++)
#pragma unroll
                for (int ni = 0; ni < 4; ni++)
                    acc[mi][ni] = __builtin_amdgcn_mfma_f32_16x16x32_bf16(
                        af[mi], bfv[ni], acc[mi][ni], 0, 0, 0);
        }
        __syncthreads();
    }

    if (z != 2) {
#pragma unroll
        for (int mi = 0; mi < 4; mi++) {
#pragma unroll
            for (int rr = 0; rr < 4; rr++) {
                float ss = 0.f;
#pragma unroll
                for (int ni = 0; ni < 4; ni++)
                    ss += acc[mi][ni][rr] * acc[mi][ni][rr];
                ss += __shfl_xor(ss, 1);
                ss += __shfl_xor(ss, 2);
                ss += __shfl_xor(ss, 4);
                ss += __shfl_xor(ss, 8);
                float inv = 1.0f / fmaxf(sqrtf(ss), 1e-6f);
#pragma unroll
                for (int ni = 0; ni < 4; ni++)
                    acc[mi][ni][rr] *= inv;
            }
        }
    }

    // epilogue: C/D layout col=lane&15, row=quad*4+reg  [verified m89/m91]
#pragma unroll
    for (int mi = 0; mi < 4; mi++) {
#pragma unroll
        for (int rr = 0; rr < 4; rr++) {
            int row = m0 + wm + mi * 16 + quad * 4 + rr;
            __hip_bfloat16* Crow = C + (size_t)row * N + n0 + wn + lrow;
#pragma unroll
            for (int ni = 0; ni < 4; ni++)
                Crow[ni * 16] = __float2bfloat16(acc[mi][ni][rr]);
        }
    }
}

// O-projection GEMM: 64x128 tile, 4 waves, fp32 C, BK=64 (LDS 24 KB),
// same rotation swizzle + XCD cluster decode.
__global__ __launch_bounds__(256) void gemm_o(
    const __hip_bfloat16* __restrict__ A,
    const __hip_bfloat16* __restrict__ W,
    float* __restrict__ C,
    int M, int N, int K)
{
    const int lid   = blockIdx.x + 8 * blockIdx.y;
    const int xcd   = lid & 7;
    const int s     = lid >> 3;
    const int m_loc = s & 15;
    const int n_loc = s >> 4;

    const int m0 = ((xcd & 3) * 16 + m_loc) * 64;
    const int n0 = ((xcd >> 2) * 4 + n_loc) * 128;

    __shared__ __hip_bfloat16 As[64 * 64];
    __shared__ __hip_bfloat16 Bs[128 * 64];

    const int t    = threadIdx.x;
    const int lane = t & 63;
    const int wv   = t >> 6;

    const int drow = lane >> 3;
    const int sl   = lane & 7;

    const int wm   = (wv >> 1) * 32;
    const int wn   = (wv & 1) * 64;
    const int lrow = lane & 15;
    const int quad = lane >> 4;

    f32x4 acc[2][4];
#pragma unroll
    for (int i = 0; i < 2; i++)
#pragma unroll
        for (int j = 0; j < 4; j++)
            acc[i][j] = (f32x4){0.f, 0.f, 0.f, 0.f};

    for (int k0 = 0; k0 < K; k0 += 64) {
#pragma unroll
        for (int inst = 0; inst < 2; inst++) {
            int r0 = wv * 16 + inst * 8;
            int r  = r0 + drow;
            int gcx = (sl - r) & 7;
            gld_lds16(A + (size_t)(m0 + r) * K + k0 + gcx * 8, &As[r0 * 64]);
        }
#pragma unroll
        for (int inst = 0; inst < 4; inst++) {
            int r0 = wv * 32 + inst * 8;
            int r  = r0 + drow;
            int gcx = (sl - r) & 7;
            gld_lds16(W + (size_t)(n0 + r) * K + k0 + gcx * 8, &Bs[r0 * 64]);
        }
        __syncthreads();

#pragma unroll
        for (int kk = 0; kk < 2; kk++) {
            bf16x8 af[2], bfv[4];
#pragma unroll
            for (int mi = 0; mi < 2; mi++) {
                int r = wm + mi * 16 + lrow;
                af[mi] = *(const bf16x8*)&As[r * 64 + ((kk * 4 + quad + r) & 7) * 8];
            }
#pragma unroll
            for (int ni = 0; ni < 4; ni++) {
                int r = wn + ni * 16 + lrow;
                bfv[ni] = *(const bf16x8*)&Bs[r * 64 + ((kk * 4 + quad + r) & 7) * 8];
            }
#pragma unroll
            for (int mi = 0; mi < 2; mi++)
#pragma unroll
                for (int ni = 0; ni < 4; ni++)
                    acc[mi][ni] = __builtin_amdgcn_mfma_f32_16x16x32_bf16(
                        af[mi], bfv[ni], acc[mi][ni], 0, 0, 0);
        }
        __syncthreads();
    }

#pragma unroll
    for (int mi = 0; mi < 2; mi++) {
#pragma unroll
        for (int rr = 0; rr < 4; rr++) {
            int row = m0 + wm + mi * 16 + quad * 4 + rr;
            float* Crow = C + (size_t)row * N + n0 + wn + lrow;
#pragma unroll
            for (int ni = 0; ni < 4; ni++)
                Crow[ni * 16] = acc[mi][ni][rr];
        }
    }
}

// MFMA sliding-window attention, 128-query blocks (8 waves, 512 thr).
// Grid 512 = exactly 2 blocks/CU, one balanced round. LDS 75 KB:
// KsP union (Ks 256x64 phase 1 / P 8x16x168 phase 2) + Vt 64x264.
__global__ __launch_bounds__(512) void attn_kernel(
    const __hip_bfloat16* __restrict__ Q,
    const __hip_bfloat16* __restrict__ K,
    const __hip_bfloat16* __restrict__ V,
    __hip_bfloat16* __restrict__ O)
{
    const int qb = blockIdx.x * 128;
    const int h  = blockIdx.y;
    const int b  = blockIdx.z;

    __shared__ __hip_bfloat16 KsP[8 * 16 * 168];  // >= 256*64; P overlay later
    __shared__ __hip_bfloat16 Vt[64 * 264];       // V^T, swizzled key blocks

    const size_t base = ((size_t)b * T_SEQ) * DMODEL + h * HDIM;
    const int t    = threadIdx.x;
    const int lane = t & 63;
    const int w    = t >> 6;                      // wave 0..7

    // K staging via DMA: wave w covers rows [w*32, w*32+32), 4 insts of 8 rows.
    {
        const int drow = lane >> 3, sl = lane & 7;
#pragma unroll
        for (int inst = 0; inst < 4; inst++) {
            int r0 = w * 32 + inst * 8;
            int r  = r0 + drow;
            int gcx = (sl - r) & 7;
            int j  = min(qb + r, T_SEQ - 1);
            gld_lds16(K + base + (size_t)j * DMODEL + gcx * 8, &KsP[r0 * 64]);
        }
    }
    // V staging: 256 tasks (dim-chunk c, key-block b0), 8x8 register transpose,
    // swizzled b128 writes: sg = (b0&~7)|((b0+c)&7).
    if (t < 256) {
        int c  = t & 7;
        int b0 = t >> 3;              // 0..31
        int sg = (b0 & ~7) | ((b0 + c) & 7);
        unsigned short m[8][8];
#pragma unroll
        for (int i = 0; i < 8; i++) {
            int j = min(qb + b0 * 8 + i, T_SEQ - 1);
            uint4 u = *(const uint4*)(V + base + (size_t)j * DMODEL + c * 8);
            unsigned short tmp[8];
            *(uint4*)tmp = u;
#pragma unroll
            for (int e = 0; e < 8; e++) m[e][i] = tmp[e];
        }
#pragma unroll
        for (int e = 0; e < 8; e++)
            *(uint4*)&Vt[(c * 8 + e) * 264 + sg * 8] = *(uint4*)m[e];
    }
    // zero tail slot 32 (keys >= 256; P is zero there but data must be finite)
    if (t < 64) {
        uint4 zz = {0, 0, 0, 0};
        *(uint4*)&Vt[t * 264 + 256] = zz;
    }
    __syncthreads();

    const int col  = lane & 15;
    const int quad = lane >> 4;
    const float slope = exp2f(-8.0f * (float)h / 15.0f);

    const __hip_bfloat16* qp = Q + base + (size_t)(qb + w * 16 + col) * DMODEL + quad * 8;
    bf16x8 qf0 = *(const bf16x8*)(qp);
    bf16x8 qf1 = *(const bf16x8*)(qp + 32);

    f32x4 sc[9];
#pragma unroll
    for (int kt = 0; kt < 9; kt++) {
        sc[kt] = (f32x4){0.f, 0.f, 0.f, 0.f};
        int r = w * 16 + kt * 16 + col;
        bf16x8 kb0 = *(const bf16x8*)&KsP[r * 64 + ((quad     + r) & 7) * 8];
        bf16x8 kb1 = *(const bf16x8*)&KsP[r * 64 + ((quad + 4 + r) & 7) * 8];
        sc[kt] = __builtin_amdgcn_mfma_f32_16x16x32_bf16(qf0, kb0, sc[kt], 0, 0, 0);
        sc[kt] = __builtin_amdgcn_mfma_f32_16x16x32_bf16(qf1, kb1, sc[kt], 0, 0, 0);
    }

    float mx[4] = {-3e38f, -3e38f, -3e38f, -3e38f};
#pragma unroll
    for (int kt = 0; kt < 9; kt++) {
#pragma unroll
        for (int r = 0; r < 4; r++) {
            int ql  = quad * 4 + r;
            int rel = kt * 16 + col - ql;
            int ka  = qb + w * 16 + kt * 16 + col;
            bool valid = (rel >= 0) && (rel < WINDOW) && (ka < T_SEQ);
            float v = valid ? (sc[kt][r] - (float)rel * slope) : -1e30f;
            sc[kt][r] = v;
            mx[r] = fmaxf(mx[r], v);
        }
    }
#pragma unroll
    for (int r = 0; r < 4; r++) {
        mx[r] = fmaxf(mx[r], __shfl_xor(mx[r], 1));
        mx[r] = fmaxf(mx[r], __shfl_xor(mx[r], 2));
        mx[r] = fmaxf(mx[r], __shfl_xor(mx[r], 4));
        mx[r] = fmaxf(mx[r], __shfl_xor(mx[r], 8));
    }
    float sm[4] = {0.f, 0.f, 0.f, 0.f};
#pragma unroll
    for (int kt = 0; kt < 9; kt++) {
#pragma unroll
        for (int r = 0; r < 4; r++) {
            float e = __expf(sc[kt][r] - mx[r]);
            sc[kt][r] = e;
            sm[r] += e;
        }
    }
#pragma unroll
    for (int r = 0; r < 4; r++) {
        sm[r] += __shfl_xor(sm[r], 1);
        sm[r] += __shfl_xor(sm[r], 2);
        sm[r] += __shfl_xor(sm[r], 4);
        sm[r] += __shfl_xor(sm[r], 8);
        sm[r] = 1.0f / sm[r];
    }

    // all Ks reads done -> overlay P (per-wave region, stride 168)
    __syncthreads();
    __hip_bfloat16* Ps = KsP + w * (16 * 168);
#pragma unroll
    for (int kt = 0; kt < 9; kt++)
#pragma unroll
        for (int r = 0; r < 4; r++)
            Ps[(quad * 4 + r) * 168 + kt * 16 + col] = __float2bfloat16(sc[kt][r] * sm[r]);
#pragma unroll
    for (int i = 0; i < 4; i++)
        Ps[(lane & 15) * 168 + 144 + quad * 4 + i] = __float2bfloat16(0.f);
    __syncthreads();

    // PV: A = P[q][key], B = Vt[dim][key] (swizzled slots)
    f32x4 o[4];
#pragma unroll
    for (int nd = 0; nd < 4; nd++) o[nd] = (f32x4){0.f, 0.f, 0.f, 0.f};
#pragma unroll
    for (int kc = 0; kc < 5; kc++) {
        bf16x8 pf = *(const bf16x8*)&Ps[col * 168 + kc * 32 + quad * 8];
        int bblk = w * 2 + kc * 4 + quad;
#pragma unroll
        for (int nd = 0; nd < 4; nd++) {
            int d  = nd * 16 + col;
            int sg = (bblk < 32) ? ((bblk & ~7) | ((bblk + (d >> 3)) & 7)) : 32;
            bf16x8 vf = *(const bf16x8*)&Vt[d * 264 + sg * 8];
            o[nd] = __builtin_amdgcn_mfma_f32_16x16x32_bf16(pf, vf, o[nd], 0, 0, 0);
        }
    }

#pragma unroll
    for (int r = 0; r < 4; r++) {
        __hip_bfloat16* op = O + base + (size_t)(qb + w * 16 + quad * 4 + r) * DMODEL + col;
#pragma unroll
        for (int nd = 0; nd < 4; nd++)
            op[nd * 16] = __float2bfloat16(o[nd][r]);
    }
}

extern "C" void kernel_launch(void* const* d_in, const int* in_sizes, int n_in,
                              void* d_out, int out_size, void* d_ws, size_t ws_size,
                              hipStream_t stream)
{
    const float* x  = (const float*)d_in[0];
    const float* Wq = (const float*)d_in[1];
    const float* Wk = (const float*)d_in[2];
    const float* Wv = (const float*)d_in[3];
    const float* Wo = (const float*)d_in[4];
    float* out = (float*)d_out;

    const size_t MT = (size_t)BATCH * T_SEQ;          // 4096 rows
    __hip_bfloat16* Qw = (__hip_bfloat16*)d_ws;       // 8 MB each (bf16)
    __hip_bfloat16* Kw = Qw + MT * DMODEL;
    __hip_bfloat16* Vw = Kw + MT * DMODEL;
    __hip_bfloat16* XA = Vw + MT * DMODEL;            // xb (pre-attn) / AO (post-attn)
    __hip_bfloat16* Wb = XA + MT * DMODEL;            // 4 x 1M bf16 weights

    cvt_kernel<<<4096, 256, 0, stream>>>(x, Wq, Wk, Wv, Wo, XA, Wb);

    dim3 g1(DMODEL / 128, MT / 128, 3);
    gemm_qkv<<<g1, 256, 0, stream>>>(
        XA, Wb, Wb + 1024 * 1024, Wb + 2 * 1024 * 1024,
        Qw, Kw, Vw, (int)MT, DMODEL, DMODEL);

    dim3 g2(T_SEQ / 128, NHEADS, BATCH);
    attn_kernel<<<g2, 512, 0, stream>>>(Qw, Kw, Vw, XA);

    dim3 g3(DMODEL / 128, MT / 64, 1);
    gemm_o<<<g3, 256, 0, stream>>>(
        XA, Wb + 3 * 1024 * 1024, out, (int)MT, DMODEL, DMODEL);
}